// Round 10
// baseline (287.122 us; speedup 1.0000x reference)
//
#include <hip/hip_runtime.h>
#include <math.h>

#define NN 2708
#define IC 1433
#define OC 128
#define NV (NN / 4)          // 677 float4/int4 per row (exact)
#define NNOC ((size_t)NN * OC)
#define NB 4096              // sort buckets
#define NW 85                // ceil(NN/32) bitmap words per row

// ---------------- bitmap of A (bit j of word w = A[i][32w+j]!=0) + zero u1/sC ----------------
__global__ __launch_bounds__(256) void bitmapA_zero(const int* __restrict__ A, unsigned* __restrict__ bm,
                                                    double* __restrict__ zd, int nzd) {
  int gid = blockIdx.x * 256 + threadIdx.x;
  if (gid < nzd) zd[gid] = 0.0;
  const int total = NN * NW;
  if (gid >= total) return;
  int i = gid / NW, w = gid - i * NW;
  const int* Ar = A + (size_t)i * NN + w * 32;
  unsigned word = 0;
  if (w < NW - 1) {
    const int4* a4 = (const int4*)Ar;
#pragma unroll
    for (int u = 0; u < 8; u++) {
      int4 a = a4[u];
      word |= (a.x != 0 ? 1u : 0u) << (4 * u);
      word |= (a.y != 0 ? 1u : 0u) << (4 * u + 1);
      word |= (a.z != 0 ? 1u : 0u) << (4 * u + 2);
      word |= (a.w != 0 ? 1u : 0u) << (4 * u + 3);
    }
  } else {
    const int nbits = NN - w * 32;
    for (int b = 0; b < nbits; b++) word |= (Ar[b] != 0 ? 1u : 0u) << b;
  }
  bm[(size_t)i * NW + w] = word;
}

// ---------------- Wt[k][o] = W[o][k] (32x32 LDS tile transpose) ----------------
__global__ __launch_bounds__(256) void transposeW(const float* __restrict__ W, float* __restrict__ Wt) {
  __shared__ float tile[32][33];
  const int t = threadIdx.x;
  const int k0 = blockIdx.x * 32, o0 = blockIdx.y * 32;
#pragma unroll
  for (int it = 0; it < 4; it++) {
    int ro = (t >> 5) + it * 8;
    int k  = k0 + (t & 31);
    tile[ro][t & 31] = (k < IC) ? W[(size_t)(o0 + ro) * IC + k] : 0.f;
  }
  __syncthreads();
#pragma unroll
  for (int it = 0; it < 4; it++) {
    int rk = (t >> 5) + it * 8;
    int k  = k0 + rk;
    if (k < IC) Wt[(size_t)k * OC + o0 + (t & 31)] = tile[t & 31][rk];
  }
}

// ---------------- w1 = W^T a1, w2 = W^T a2 from Wt (fp64, one wave per column c) ----------------
__global__ __launch_bounds__(256) void wvec_t(const float* __restrict__ Wt, const float* __restrict__ a1,
                                              const float* __restrict__ a2,
                                              double* __restrict__ w1, double* __restrict__ w2) {
  const int t = threadIdx.x;
  const int wv = t >> 6, lane = t & 63;
  const int c = blockIdx.x * 4 + wv;
  if (c >= IC) return;
  const float* Wr = Wt + (size_t)c * OC;
  double wa = (double)Wr[lane], wb = (double)Wr[64 + lane];
  double s1 = fma(wa, (double)a1[lane], wb * (double)a1[64 + lane]);
  double s2 = fma(wa, (double)a2[lane], wb * (double)a2[64 + lane]);
  for (int o = 32; o; o >>= 1) { s1 += __shfl_down(s1, o, 64); s2 += __shfl_down(s2, o, 64); }
  if (lane == 0) { w1[c] = s1; w2[c] = s2; }
}

// ---------------- k1 = X@w1, k2 = X@w2 (fp64), one wave per row ----------------
__global__ __launch_bounds__(256) void xw(const float* __restrict__ X, const double* __restrict__ w1,
                                          const double* __restrict__ w2,
                                          double* __restrict__ k1, double* __restrict__ k2) {
  __shared__ double w1s[IC];
  __shared__ double w2s[IC];
  const int t = threadIdx.x;
  for (int c = t; c < IC; c += 256) { w1s[c] = w1[c]; w2s[c] = w2[c]; }
  __syncthreads();
  const int wave = t >> 6, lane = t & 63;
  const int i = blockIdx.x * 4 + wave;
  if (i >= NN) return;
  const float* Xi = X + (size_t)i * IC;
  double s1 = 0.0, s2 = 0.0;
  for (int c = lane; c < IC; c += 64) {
    double x = (double)Xi[c];
    s1 = fma(x, w1s[c], s1);
    s2 = fma(x, w2s[c], s2);
  }
  for (int o = 32; o; o >>= 1) { s1 += __shfl_down(s1, o, 64); s2 += __shfl_down(s2, o, 64); }
  if (lane == 0) { k1[i] = s1; k2[i] = s2; }
}

// ---------------- K partials: Kp[split] = X @ Wt over k-chunk (fp32, conflict-free LDS) ----------------
__global__ __launch_bounds__(256) void gemmK(const float* __restrict__ X, const float* __restrict__ Wt,
                                             float* __restrict__ Kp, int chunk) {
  __shared__ float Xs[32][36];
  __shared__ float Ws[32][132];
  const int t  = threadIdx.x;
  const int rb = blockIdx.x * 32;
  const int ks = blockIdx.y * chunk;
  const int ke = min(IC, ks + chunk);
  float* __restrict__ Ko = Kp + (size_t)blockIdx.y * NNOC;
  const int row0 = (t >> 5) * 4;
  const int col4 = (t & 31) * 4;
  float acc[4][4];
#pragma unroll
  for (int r = 0; r < 4; r++)
#pragma unroll
    for (int c = 0; c < 4; c++) acc[r][c] = 0.f;

  for (int kb = ks; kb < ke; kb += 32) {
#pragma unroll
    for (int it = 0; it < 4; it++) {
      int idx = t + it * 256;
      int r = idx >> 5, c = idx & 31;
      int gr = rb + r, gc = kb + c;
      Xs[r][c] = (gr < NN && gc < ke) ? X[(size_t)gr * IC + gc] : 0.f;
    }
#pragma unroll
    for (int it = 0; it < 4; it++) {
      int idx4 = t + it * 256;
      int k = idx4 >> 5, cg = (idx4 & 31) * 4;
      int gk = kb + k;
      float4 v = make_float4(0.f, 0.f, 0.f, 0.f);
      if (gk < ke) v = *reinterpret_cast<const float4*>(&Wt[(size_t)gk * OC + cg]);
      *reinterpret_cast<float4*>(&Ws[k][cg]) = v;
    }
    __syncthreads();
#pragma unroll
    for (int g = 0; g < 8; g++) {
      float xr[4][4];
#pragma unroll
      for (int r = 0; r < 4; r++)
        *reinterpret_cast<float4*>(xr[r]) = *reinterpret_cast<const float4*>(&Xs[row0 + r][g * 4]);
#pragma unroll
      for (int j = 0; j < 4; j++) {
        const float4 w4 = *reinterpret_cast<const float4*>(&Ws[g * 4 + j][col4]);
#pragma unroll
        for (int r = 0; r < 4; r++) {
          acc[r][0] = fmaf(xr[r][j], w4.x, acc[r][0]);
          acc[r][1] = fmaf(xr[r][j], w4.y, acc[r][1]);
          acc[r][2] = fmaf(xr[r][j], w4.z, acc[r][2]);
          acc[r][3] = fmaf(xr[r][j], w4.w, acc[r][3]);
        }
      }
    }
    __syncthreads();
  }
#pragma unroll
  for (int r = 0; r < 4; r++) {
    int gr = rb + row0 + r;
    if (gr < NN) {
      float4 v = make_float4(acc[r][0], acc[r][1], acc[r][2], acc[r][3]);
      *reinterpret_cast<float4*>(&Ko[(size_t)gr * OC + col4]) = v;
    }
  }
}

// ---------------- merge split-K partials (float4, nsplit-generic) ----------------
__global__ __launch_bounds__(256) void mergeK(const float4* __restrict__ Kp, float4* __restrict__ Kf, int nsplit) {
  size_t i = (size_t)blockIdx.x * 256 + threadIdx.x;
  const size_t n4 = NNOC / 4;
  if (i >= n4) return;
  float4 s = Kp[i];
  for (int ps = 1; ps < nsplit; ps++) {
    float4 v = Kp[(size_t)ps * n4 + i];
    s.x += v.x; s.y += v.y; s.z += v.z; s.w += v.w;
  }
  Kf[i] = s;
}

// ---------------- u1 = U^T@k1, s = U^T@1 (fp64, float4 cols) ----------------
__global__ __launch_bounds__(256) void ut_reduce(const float4* __restrict__ U4, const double* __restrict__ k1,
                                                 double* __restrict__ u1, double* __restrict__ s) {
  int c4 = blockIdx.x * 256 + threadIdx.x;
  if (c4 >= NV) return;
  int r0 = blockIdx.y * 32;
  int r1 = min(NN, r0 + 32);
  double au0 = 0, au1_ = 0, au2 = 0, au3 = 0, as0 = 0, as1 = 0, as2 = 0, as3 = 0;
  for (int r = r0; r < r1; r++) {
    float4 u = U4[(size_t)r * NV + c4];
    double kr = k1[r];
    au0 = fma((double)u.x, kr, au0); au1_ = fma((double)u.y, kr, au1_);
    au2 = fma((double)u.z, kr, au2); au3 = fma((double)u.w, kr, au3);
    as0 += (double)u.x; as1 += (double)u.y; as2 += (double)u.z; as3 += (double)u.w;
  }
  int c = c4 * 4;
  atomicAdd(&u1[c + 0], au0); atomicAdd(&u1[c + 1], au1_);
  atomicAdd(&u1[c + 2], au2); atomicAdd(&u1[c + 3], au3);
  atomicAdd(&s[c + 0], as0);  atomicAdd(&s[c + 1], as1);
  atomicAdd(&s[c + 2], as2);  atomicAdd(&s[c + 3], as3);
}

// ---------------- p = U@(lmbd*u1), q = U@(lmbd*s) (fp64), one wave per row ----------------
__global__ __launch_bounds__(256) void uv_kernel(const float4* __restrict__ U4, const float4* __restrict__ L4,
                                                 const double2* __restrict__ u1d, const double2* __restrict__ sd,
                                                 double* __restrict__ p, double* __restrict__ q) {
  const int t = threadIdx.x;
  const int wave = t >> 6, lane = t & 63;
  const int r = blockIdx.x * 4 + wave;
  if (r >= NN) return;
  const float4* Ur = U4 + (size_t)r * NV;
  double ap = 0.0, aq = 0.0;
  for (int c4 = lane; c4 < NV; c4 += 64) {
    float4 u = Ur[c4];
    float4 lm = L4[c4];
    double2 ua = u1d[c4 * 2], ub = u1d[c4 * 2 + 1];
    double2 sa = sd[c4 * 2],  sb = sd[c4 * 2 + 1];
    ap = fma((double)u.x, (double)lm.x * ua.x, ap);
    ap = fma((double)u.y, (double)lm.y * ua.y, ap);
    ap = fma((double)u.z, (double)lm.z * ub.x, ap);
    ap = fma((double)u.w, (double)lm.w * ub.y, ap);
    aq = fma((double)u.x, (double)lm.x * sa.x, aq);
    aq = fma((double)u.y, (double)lm.y * sa.y, aq);
    aq = fma((double)u.z, (double)lm.z * sb.x, aq);
    aq = fma((double)u.w, (double)lm.w * sb.y, aq);
  }
  for (int o = 32; o; o >>= 1) { ap += __shfl_down(ap, o, 64); aq += __shfl_down(aq, o, 64); }
  if (lane == 0) { p[r] = ap; q[r] = aq; }
}

// ---------------- fused bucket sort of k2 (one block) ----------------
__global__ __launch_bounds__(1024) void sortk2(const double* __restrict__ k2,
                                               double* __restrict__ kvd, int* __restrict__ sortedj,
                                               double* __restrict__ hdr) {
  __shared__ int hist[NB];
  __shared__ int ps[1024];
  __shared__ double rmn[16], rmx[16];
  __shared__ double mn_sh, sc_sh;
  const int t = threadIdx.x, wv = t >> 6, ln = t & 63;

  double mn = 1e300, mx = -1e300;
  for (int j = t; j < NN; j += 1024) { double v = k2[j]; mn = fmin(mn, v); mx = fmax(mx, v); }
  for (int o = 32; o; o >>= 1) { mn = fmin(mn, __shfl_xor(mn, o, 64)); mx = fmax(mx, __shfl_xor(mx, o, 64)); }
  if (ln == 0) { rmn[wv] = mn; rmx[wv] = mx; }
  for (int b = t; b < NB; b += 1024) hist[b] = 0;
  __syncthreads();
  if (t == 0) {
    double amn = rmn[0], amx = rmx[0];
    for (int u = 1; u < 16; u++) { amn = fmin(amn, rmn[u]); amx = fmax(amx, rmx[u]); }
    hdr[0] = amn; hdr[1] = amx;
    mn_sh = amn; sc_sh = NB / fmax(amx - amn, 1e-30);
  }
  __syncthreads();
  const double minv = mn_sh, scale = sc_sh;
  for (int j = t; j < NN; j += 1024) {
    int b = min(NB - 1, max(0, (int)((k2[j] - minv) * scale)));
    atomicAdd(&hist[b], 1);
  }
  __syncthreads();
  int4 v4 = ((const int4*)hist)[t];
  int s = v4.x + v4.y + v4.z + v4.w;
  ps[t] = s;
  __syncthreads();
  for (int d = 1; d < 1024; d <<= 1) {
    int x = (t >= d) ? ps[t - d] : 0;
    __syncthreads();
    ps[t] += x;
    __syncthreads();
  }
  int excl = ps[t] - s;
  hist[4 * t]     = excl;
  hist[4 * t + 1] = excl + v4.x;
  hist[4 * t + 2] = excl + v4.x + v4.y;
  hist[4 * t + 3] = excl + v4.x + v4.y + v4.z;
  __syncthreads();
  for (int j = t; j < NN; j += 1024) {
    double v = k2[j];
    int b = min(NB - 1, max(0, (int)((v - minv) * scale)));
    int pos = atomicAdd(&hist[b], 1);
    kvd[pos] = v;
    sortedj[pos] = j;
  }
}

// ======== shared walk body (macro-free duplication kept readable) ========
// Phase 1: walk + weights; DUMP candidate lists to global (no gather).
__global__ __launch_bounds__(256) void softmax_walk(const unsigned* __restrict__ bm,
                                                    const double* __restrict__ p, const double* __restrict__ q,
                                                    const double* __restrict__ kvd, const int* __restrict__ sortedj,
                                                    const double* __restrict__ hdr,
                                                    short* __restrict__ jsG, float* __restrict__ wG,
                                                    int* __restrict__ nlistG, float* __restrict__ sumwG,
                                                    int maxc) {
  __shared__ float vf[NN];
  __shared__ short js[NN];
  __shared__ int wcnt[4];
  __shared__ double wfv[4], wbnd[4];
  __shared__ float redf[4];

  const int i = blockIdx.x;
  const int t = threadIdx.x;
  const int wv = t >> 6, lane = t & 63;
  const double pi = p[i], qi = q[i];
  const double bw = (hdr[1] - hdr[0]) * (1.0 / NB);
  const double margin = 36.0 + 2.0 * fabs(qi) * bw;
  const unsigned* bmrow = bm + (size_t)i * NW;
  const bool sgn = (qi >= 0.0);
  const unsigned long long ltmask = (1ull << lane) - 1ull;
  int nlist = 0;
  double m_lb = -1e300;

  int coveredA = 0;
  for (int r = 0; r * 256 < NN; r++) {
    int idx = r * 256 + t;
    bool ok = idx < NN;
    double v = 0.0; int j = 0; unsigned a = 0;
    if (ok) {
      int pos = sgn ? (NN - 1 - idx) : idx;
      v = fma(qi, kvd[pos], pi);
      j = sortedj[pos];
      a = (bmrow[j >> 5] >> (j & 31)) & 1u;
    }
    bool isn = ok && a;
    unsigned long long mask = __ballot(isn);
    int wo = __popcll(mask & ltmask);
    double fv = isn ? fabs(v) : -1e300;
    double bnd = ok ? v : 1e300;
    for (int o = 32; o; o >>= 1) {
      fv = fmax(fv, __shfl_xor(fv, o, 64));
      bnd = fmin(bnd, __shfl_xor(bnd, o, 64));
    }
    if (lane == 0) { wcnt[wv] = __popcll(mask); wfv[wv] = fv; wbnd[wv] = bnd; }
    __syncthreads();
    int c0 = wcnt[0], c1 = wcnt[1], c2 = wcnt[2], c3 = wcnt[3];
    int base = nlist + (wv > 0 ? c0 : 0) + (wv > 1 ? c1 : 0) + (wv > 2 ? c2 : 0);
    if (isn) { js[base + wo] = (short)j; vf[base + wo] = (float)v; }
    nlist += c0 + c1 + c2 + c3;
    m_lb = fmax(m_lb, fmax(fmax(wfv[0], wfv[1]), fmax(wfv[2], wfv[3])));
    double rbnd = fmin(fmin(wbnd[0], wbnd[1]), fmin(wbnd[2], wbnd[3]));
    __syncthreads();
    coveredA = min(NN, (r + 1) * 256);
    if (rbnd < m_lb - margin) break;
  }
  const int remB = NN - coveredA;

  for (int r = 0; r * 256 < remB; r++) {
    int idx = r * 256 + t;
    bool ok = idx < remB;
    double v = 0.0; int j = 0; unsigned a = 0;
    if (ok) {
      int pos = sgn ? idx : (NN - 1 - idx);
      v = fma(qi, kvd[pos], pi);
      j = sortedj[pos];
      a = (bmrow[j >> 5] >> (j & 31)) & 1u;
    }
    bool isn = ok && a;
    unsigned long long mask = __ballot(isn);
    int wo = __popcll(mask & ltmask);
    double fv = isn ? fabs(v) : -1e300;
    double bnd = ok ? v : -1e300;
    for (int o = 32; o; o >>= 1) {
      fv = fmax(fv, __shfl_xor(fv, o, 64));
      bnd = fmax(bnd, __shfl_xor(bnd, o, 64));
    }
    if (lane == 0) { wcnt[wv] = __popcll(mask); wfv[wv] = fv; wbnd[wv] = bnd; }
    __syncthreads();
    int c0 = wcnt[0], c1 = wcnt[1], c2 = wcnt[2], c3 = wcnt[3];
    int base = nlist + (wv > 0 ? c0 : 0) + (wv > 1 ? c1 : 0) + (wv > 2 ? c2 : 0);
    if (isn) { js[base + wo] = (short)j; vf[base + wo] = (float)v; }
    nlist += c0 + c1 + c2 + c3;
    m_lb = fmax(m_lb, fmax(fmax(wfv[0], wfv[1]), fmax(wfv[2], wfv[3])));
    double rbnd = fmax(fmax(wbnd[0], wbnd[1]), fmax(wbnd[2], wbnd[3]));
    __syncthreads();
    if (-rbnd < m_lb - margin) break;
  }

  const float fm = (float)m_lb;
  float sw = 0.f;
  for (int c = t; c < nlist; c += 256) {
    float w = __expf(fabsf(vf[c]) - fm);
    vf[c] = w;
    sw += w;
  }
  for (int o = 32; o; o >>= 1) sw += __shfl_xor(sw, o, 64);
  if (lane == 0) redf[wv] = sw;
  __syncthreads();
  const float sumw = (redf[0] + redf[1]) + (redf[2] + redf[3]);

  const int nl = min(nlist, maxc);
  if (t == 0) { nlistG[i] = nl; sumwG[i] = sumw; }
  short* jd = jsG + (size_t)i * maxc;
  float* wd = wG + (size_t)i * maxc;
  for (int c = t; c < nl; c += 256) { jd[c] = js[c]; wd[c] = vf[c]; }
}

// Phase 2: slice-parallel gather. grid (NN, G); 2 cand-groups x 128 channels.
__global__ __launch_bounds__(256) void gatherH(const short* __restrict__ jsG, const float* __restrict__ wG,
                                               const int* __restrict__ nlistG,
                                               const float* __restrict__ K, float* __restrict__ Hpart,
                                               int maxc) {
  __shared__ float hp[2][128];
  const int i = blockIdx.x, y = blockIdx.y, G = gridDim.y;
  const int t = threadIdx.x;
  const int ch = t & 127, g = t >> 7;
  const int nl = nlistG[i];
  const short* jl = jsG + (size_t)i * maxc;
  const float* wl = wG + (size_t)i * maxc;
  float acc = 0.f;
  const int st = 2 * G;
  int c = y + g * G;
  for (; c + st < nl; c += 2 * st) {
    float w0 = wl[c], w1 = wl[c + st];
    int j0 = jl[c], j1 = jl[c + st];
    float k0 = K[(size_t)j0 * OC + ch];
    float k1 = K[(size_t)j1 * OC + ch];
    acc = fmaf(w0, k0, acc);
    acc = fmaf(w1, k1, acc);
  }
  for (; c < nl; c += st)
    acc = fmaf(wl[c], K[(size_t)jl[c] * OC + ch], acc);
  hp[g][ch] = acc;
  __syncthreads();
  if (t < 128)
    Hpart[((size_t)i * G + y) * OC + t] = hp[0][t] + hp[1][t];
}

// Phase 3: H = (sum_y Hpart) / sumw
__global__ __launch_bounds__(256) void reduceH(const float* __restrict__ Hpart, const float* __restrict__ sumwG,
                                               float* __restrict__ H, int G) {
  int gid = blockIdx.x * 256 + threadIdx.x;
  if (gid >= (int)NNOC) return;
  int i = gid >> 7, ch = gid & 127;
  float s = 0.f;
  for (int y = 0; y < G; y++) s += Hpart[((size_t)i * G + y) * OC + ch];
  H[gid] = s / sumwG[i];
}

// ---------------- fused fallback (R9 version) for small workspaces ----------------
__global__ __launch_bounds__(256) void softmaxH_fused(const unsigned* __restrict__ bm,
                                                      const double* __restrict__ p, const double* __restrict__ q,
                                                      const double* __restrict__ kvd, const int* __restrict__ sortedj,
                                                      const double* __restrict__ hdr,
                                                      const float* __restrict__ K, float* __restrict__ H) {
  __shared__ float vf[NN];
  __shared__ short js[NN];
  __shared__ float hpart[4][128];
  __shared__ int wcnt[4];
  __shared__ double wfv[4], wbnd[4];
  __shared__ float redf[4];

  const int i = blockIdx.x;
  const int t = threadIdx.x;
  const int wv = t >> 6, lane = t & 63;
  const double pi = p[i], qi = q[i];
  const double bw = (hdr[1] - hdr[0]) * (1.0 / NB);
  const double margin = 36.0 + 2.0 * fabs(qi) * bw;
  const unsigned* bmrow = bm + (size_t)i * NW;
  const bool sgn = (qi >= 0.0);
  const unsigned long long ltmask = (1ull << lane) - 1ull;
  int nlist = 0;
  double m_lb = -1e300;

  int coveredA = 0;
  for (int r = 0; r * 256 < NN; r++) {
    int idx = r * 256 + t;
    bool ok = idx < NN;
    double v = 0.0; int j = 0; unsigned a = 0;
    if (ok) {
      int pos = sgn ? (NN - 1 - idx) : idx;
      v = fma(qi, kvd[pos], pi);
      j = sortedj[pos];
      a = (bmrow[j >> 5] >> (j & 31)) & 1u;
    }
    bool isn = ok && a;
    unsigned long long mask = __ballot(isn);
    int wo = __popcll(mask & ltmask);
    double fv = isn ? fabs(v) : -1e300;
    double bnd = ok ? v : 1e300;
    for (int o = 32; o; o >>= 1) {
      fv = fmax(fv, __shfl_xor(fv, o, 64));
      bnd = fmin(bnd, __shfl_xor(bnd, o, 64));
    }
    if (lane == 0) { wcnt[wv] = __popcll(mask); wfv[wv] = fv; wbnd[wv] = bnd; }
    __syncthreads();
    int c0 = wcnt[0], c1 = wcnt[1], c2 = wcnt[2], c3 = wcnt[3];
    int base = nlist + (wv > 0 ? c0 : 0) + (wv > 1 ? c1 : 0) + (wv > 2 ? c2 : 0);
    if (isn) { js[base + wo] = (short)j; vf[base + wo] = (float)v; }
    nlist += c0 + c1 + c2 + c3;
    m_lb = fmax(m_lb, fmax(fmax(wfv[0], wfv[1]), fmax(wfv[2], wfv[3])));
    double rbnd = fmin(fmin(wbnd[0], wbnd[1]), fmin(wbnd[2], wbnd[3]));
    __syncthreads();
    coveredA = min(NN, (r + 1) * 256);
    if (rbnd < m_lb - margin) break;
  }
  const int remB = NN - coveredA;

  for (int r = 0; r * 256 < remB; r++) {
    int idx = r * 256 + t;
    bool ok = idx < remB;
    double v = 0.0; int j = 0; unsigned a = 0;
    if (ok) {
      int pos = sgn ? idx : (NN - 1 - idx);
      v = fma(qi, kvd[pos], pi);
      j = sortedj[pos];
      a = (bmrow[j >> 5] >> (j & 31)) & 1u;
    }
    bool isn = ok && a;
    unsigned long long mask = __ballot(isn);
    int wo = __popcll(mask & ltmask);
    double fv = isn ? fabs(v) : -1e300;
    double bnd = ok ? v : -1e300;
    for (int o = 32; o; o >>= 1) {
      fv = fmax(fv, __shfl_xor(fv, o, 64));
      bnd = fmax(bnd, __shfl_xor(bnd, o, 64));
    }
    if (lane == 0) { wcnt[wv] = __popcll(mask); wfv[wv] = fv; wbnd[wv] = bnd; }
    __syncthreads();
    int c0 = wcnt[0], c1 = wcnt[1], c2 = wcnt[2], c3 = wcnt[3];
    int base = nlist + (wv > 0 ? c0 : 0) + (wv > 1 ? c1 : 0) + (wv > 2 ? c2 : 0);
    if (isn) { js[base + wo] = (short)j; vf[base + wo] = (float)v; }
    nlist += c0 + c1 + c2 + c3;
    m_lb = fmax(m_lb, fmax(fmax(wfv[0], wfv[1]), fmax(wfv[2], wfv[3])));
    double rbnd = fmax(fmax(wbnd[0], wbnd[1]), fmax(wbnd[2], wbnd[3]));
    __syncthreads();
    if (-rbnd < m_lb - margin) break;
  }

  const float fm = (float)m_lb;
  float sw = 0.f;
  for (int c = t; c < nlist; c += 256) {
    float w = __expf(fabsf(vf[c]) - fm);
    vf[c] = w;
    sw += w;
  }
  for (int o = 32; o; o >>= 1) sw += __shfl_xor(sw, o, 64);
  if (lane == 0) redf[wv] = sw;
  __syncthreads();
  const float sumw = (redf[0] + redf[1]) + (redf[2] + redf[3]);

  const int ch = t & 63, g = t >> 6;
  float a0 = 0.f, a1 = 0.f;
  int c = g;
  for (; c + 4 < nlist; c += 8) {
    float w0 = vf[c], w1 = vf[c + 4];
    const float* K0 = K + (size_t)js[c] * OC;
    const float* K1 = K + (size_t)js[c + 4] * OC;
    float k00 = K0[ch], k01 = K0[64 + ch];
    float k10 = K1[ch], k11 = K1[64 + ch];
    a0 = fmaf(w0, k00, a0); a1 = fmaf(w0, k01, a1);
    a0 = fmaf(w1, k10, a0); a1 = fmaf(w1, k11, a1);
  }
  for (; c < nlist; c += 4) {
    float w = vf[c];
    const float* Kr = K + (size_t)js[c] * OC;
    a0 = fmaf(w, Kr[ch], a0);
    a1 = fmaf(w, Kr[64 + ch], a1);
  }
  hpart[g][ch] = a0;
  hpart[g][64 + ch] = a1;
  __syncthreads();
  if (t < 128) {
    float hv = (hpart[0][t] + hpart[1][t]) + (hpart[2][t] + hpart[3][t]);
    H[(size_t)i * OC + t] = hv / sumw;
  }
}

extern "C" void kernel_launch(void* const* d_in, const int* in_sizes, int n_in,
                              void* d_out, int out_size, void* d_ws, size_t ws_size,
                              hipStream_t stream) {
  const float* X    = (const float*)d_in[0];
  const int*   A    = (const int*)d_in[1];
  const float* U    = (const float*)d_in[2];
  const float* W    = (const float*)d_in[3];
  const float* a1   = (const float*)d_in[4];
  const float* a2   = (const float*)d_in[5];
  const float* lmbd = (const float*)d_in[6];
  float* H = (float*)d_out;

  const size_t wt_bytes  = (size_t)IC * OC * 4;
  const size_t bm_bytes  = (size_t)NN * NW * 4;
  const size_t dbl_bytes = (size_t)(7 * NN + 2 * IC + 2) * 8;

  // config cascade: (nsplit, G, MAXC); G=0 => fused fallback
  const int cfgs[9][3] = {{8,8,2048},{8,8,1536},{8,4,1536},{4,4,1536},{2,4,1536},
                          {8,0,0},{4,0,0},{2,0,0},{1,0,0}};
  int nsplit = 1, G = 0, MAXC = 0;
  for (int ci = 0; ci < 9; ci++) {
    int ns = cfgs[ci][0], g = cfgs[ci][1], mc = cfgs[ci][2];
    size_t need = (size_t)(ns > 1 ? ns + 1 : 1) * NNOC * 4 + wt_bytes + dbl_bytes +
                  (size_t)NN * 4 + bm_bytes + 1024;
    if (g > 0)
      need += (size_t)NN * mc * 2 + (size_t)NN * mc * 4 +
              (size_t)NN * g * OC * 4 + (size_t)NN * 8;
    if (need <= ws_size) { nsplit = ns; G = g; MAXC = mc; break; }
  }

  char* base = (char*)d_ws;
  float* Kp = (float*)base;
  float* Kf = (nsplit > 1) ? (float*)(base + (size_t)nsplit * NNOC * 4) : Kp;
  size_t off = (size_t)(nsplit > 1 ? nsplit + 1 : 1) * NNOC * 4;
  float* Wt = (float*)(base + off);            off += wt_bytes;
  double* dbl = (double*)(base + off);         off += dbl_bytes;
  double* k1  = dbl;
  double* k2  = k1 + NN;
  double* u1  = k2 + NN;
  double* sC  = u1 + NN;
  double* p   = sC + NN;
  double* q   = p  + NN;
  double* kvd = q  + NN;
  double* w1  = kvd + NN;
  double* w2  = w1 + IC;
  double* hdr = w2 + IC;
  int* sortedj = (int*)(base + off);           off += (size_t)NN * 4;
  unsigned* bm = (unsigned*)(base + off);      off += bm_bytes;
  float* wG = nullptr; float* Hpart = nullptr; float* sumwG = nullptr;
  int* nlistG = nullptr; short* jsG = nullptr;
  if (G > 0) {
    wG     = (float*)(base + off);             off += (size_t)NN * MAXC * 4;
    Hpart  = (float*)(base + off);             off += (size_t)NN * G * OC * 4;
    sumwG  = (float*)(base + off);             off += (size_t)NN * 4;
    nlistG = (int*)(base + off);               off += (size_t)NN * 4;
    jsG    = (short*)(base + off);             off += (size_t)NN * MAXC * 2;
  }

  const int chunk = (IC + nsplit - 1) / nsplit;

  bitmapA_zero<<<(NN * NW + 255) / 256, 256, 0, stream>>>(A, bm, u1, 2 * NN);
  transposeW<<<dim3((IC + 31) / 32, OC / 32), 256, 0, stream>>>(W, Wt);
  wvec_t<<<(IC + 3) / 4, 256, 0, stream>>>(Wt, a1, a2, w1, w2);
  xw<<<NN / 4, 256, 0, stream>>>(X, w1, w2, k1, k2);
  gemmK<<<dim3((NN + 31) / 32, nsplit), 256, 0, stream>>>(X, Wt, Kp, chunk);
  if (nsplit > 1)
    mergeK<<<(int)((NNOC / 4 + 255) / 256), 256, 0, stream>>>((const float4*)Kp, (float4*)Kf, nsplit);
  ut_reduce<<<dim3((NV + 255) / 256, (NN + 31) / 32), 256, 0, stream>>>((const float4*)U, k1, u1, sC);
  uv_kernel<<<NN / 4, 256, 0, stream>>>((const float4*)U, (const float4*)lmbd,
                                        (const double2*)u1, (const double2*)sC, p, q);
  sortk2<<<1, 1024, 0, stream>>>(k2, kvd, sortedj, hdr);
  if (G > 0) {
    softmax_walk<<<NN, 256, 0, stream>>>(bm, p, q, kvd, sortedj, hdr, jsG, wG, nlistG, sumwG, MAXC);
    gatherH<<<dim3(NN, G), 256, 0, stream>>>(jsG, wG, nlistG, Kf, Hpart, MAXC);
    reduceH<<<(int)((NNOC + 255) / 256), 256, 0, stream>>>(Hpart, sumwG, H, G);
  } else {
    softmaxH_fused<<<NN, 256, 0, stream>>>(bm, p, q, kvd, sortedj, hdr, Kf, H);
  }
}

// Round 11
// 276.251 us; speedup vs baseline: 1.0394x; 1.0394x over previous
//
#include <hip/hip_runtime.h>
#include <math.h>

#define NN 2708
#define IC 1433
#define OC 128
#define NV (NN / 4)          // 677 float4/int4 per row (exact)
#define NNOC ((size_t)NN * OC)
#define NB 4096              // sort buckets
#define NW 85                // ceil(NN/32) bitmap words per row

// ---------------- bitmap of A (bit j of word w = A[i][32w+j]!=0) + zero u1/sC ----------------
__global__ __launch_bounds__(256) void bitmapA_zero(const int* __restrict__ A, unsigned* __restrict__ bm,
                                                    double* __restrict__ zd, int nzd) {
  int gid = blockIdx.x * 256 + threadIdx.x;
  if (gid < nzd) zd[gid] = 0.0;
  const int total = NN * NW;
  if (gid >= total) return;
  int i = gid / NW, w = gid - i * NW;
  const int* Ar = A + (size_t)i * NN + w * 32;
  unsigned word = 0;
  if (w < NW - 1) {
    const int4* a4 = (const int4*)Ar;
#pragma unroll
    for (int u = 0; u < 8; u++) {
      int4 a = a4[u];
      word |= (a.x != 0 ? 1u : 0u) << (4 * u);
      word |= (a.y != 0 ? 1u : 0u) << (4 * u + 1);
      word |= (a.z != 0 ? 1u : 0u) << (4 * u + 2);
      word |= (a.w != 0 ? 1u : 0u) << (4 * u + 3);
    }
  } else {
    const int nbits = NN - w * 32;
    for (int b = 0; b < nbits; b++) word |= (Ar[b] != 0 ? 1u : 0u) << b;
  }
  bm[(size_t)i * NW + w] = word;
}

// ---------------- Wt[k][o] = W[o][k] (32x32 LDS tile transpose) ----------------
__global__ __launch_bounds__(256) void transposeW(const float* __restrict__ W, float* __restrict__ Wt) {
  __shared__ float tile[32][33];
  const int t = threadIdx.x;
  const int k0 = blockIdx.x * 32, o0 = blockIdx.y * 32;
#pragma unroll
  for (int it = 0; it < 4; it++) {
    int ro = (t >> 5) + it * 8;
    int k  = k0 + (t & 31);
    tile[ro][t & 31] = (k < IC) ? W[(size_t)(o0 + ro) * IC + k] : 0.f;
  }
  __syncthreads();
#pragma unroll
  for (int it = 0; it < 4; it++) {
    int rk = (t >> 5) + it * 8;
    int k  = k0 + rk;
    if (k < IC) Wt[(size_t)k * OC + o0 + (t & 31)] = tile[t & 31][rk];
  }
}

// ---------------- w1 = W^T a1, w2 = W^T a2 from Wt (fp64, one wave per column c) ----------------
__global__ __launch_bounds__(256) void wvec_t(const float* __restrict__ Wt, const float* __restrict__ a1,
                                              const float* __restrict__ a2,
                                              double* __restrict__ w1, double* __restrict__ w2) {
  const int t = threadIdx.x;
  const int wv = t >> 6, lane = t & 63;
  const int c = blockIdx.x * 4 + wv;
  if (c >= IC) return;
  const float* Wr = Wt + (size_t)c * OC;
  double wa = (double)Wr[lane], wb = (double)Wr[64 + lane];
  double s1 = fma(wa, (double)a1[lane], wb * (double)a1[64 + lane]);
  double s2 = fma(wa, (double)a2[lane], wb * (double)a2[64 + lane]);
  for (int o = 32; o; o >>= 1) { s1 += __shfl_down(s1, o, 64); s2 += __shfl_down(s2, o, 64); }
  if (lane == 0) { w1[c] = s1; w2[c] = s2; }
}

// ---------------- k1 = X@w1, k2 = X@w2 (fp64), one wave per row ----------------
__global__ __launch_bounds__(256) void xw(const float* __restrict__ X, const double* __restrict__ w1,
                                          const double* __restrict__ w2,
                                          double* __restrict__ k1, double* __restrict__ k2) {
  __shared__ double w1s[IC];
  __shared__ double w2s[IC];
  const int t = threadIdx.x;
  for (int c = t; c < IC; c += 256) { w1s[c] = w1[c]; w2s[c] = w2[c]; }
  __syncthreads();
  const int wave = t >> 6, lane = t & 63;
  const int i = blockIdx.x * 4 + wave;
  if (i >= NN) return;
  const float* Xi = X + (size_t)i * IC;
  double s1 = 0.0, s2 = 0.0;
  for (int c = lane; c < IC; c += 64) {
    double x = (double)Xi[c];
    s1 = fma(x, w1s[c], s1);
    s2 = fma(x, w2s[c], s2);
  }
  for (int o = 32; o; o >>= 1) { s1 += __shfl_down(s1, o, 64); s2 += __shfl_down(s2, o, 64); }
  if (lane == 0) { k1[i] = s1; k2[i] = s2; }
}

// ---------------- K partials: Kp[split] = X @ Wt over k-chunk (fp32, conflict-free LDS) ----------------
__global__ __launch_bounds__(256) void gemmK(const float* __restrict__ X, const float* __restrict__ Wt,
                                             float* __restrict__ Kp, int chunk) {
  __shared__ float Xs[32][36];
  __shared__ float Ws[32][132];
  const int t  = threadIdx.x;
  const int rb = blockIdx.x * 32;
  const int ks = blockIdx.y * chunk;
  const int ke = min(IC, ks + chunk);
  float* __restrict__ Ko = Kp + (size_t)blockIdx.y * NNOC;
  const int row0 = (t >> 5) * 4;
  const int col4 = (t & 31) * 4;
  float acc[4][4];
#pragma unroll
  for (int r = 0; r < 4; r++)
#pragma unroll
    for (int c = 0; c < 4; c++) acc[r][c] = 0.f;

  for (int kb = ks; kb < ke; kb += 32) {
#pragma unroll
    for (int it = 0; it < 4; it++) {
      int idx = t + it * 256;
      int r = idx >> 5, c = idx & 31;
      int gr = rb + r, gc = kb + c;
      Xs[r][c] = (gr < NN && gc < ke) ? X[(size_t)gr * IC + gc] : 0.f;
    }
#pragma unroll
    for (int it = 0; it < 4; it++) {
      int idx4 = t + it * 256;
      int k = idx4 >> 5, cg = (idx4 & 31) * 4;
      int gk = kb + k;
      float4 v = make_float4(0.f, 0.f, 0.f, 0.f);
      if (gk < ke) v = *reinterpret_cast<const float4*>(&Wt[(size_t)gk * OC + cg]);
      *reinterpret_cast<float4*>(&Ws[k][cg]) = v;
    }
    __syncthreads();
#pragma unroll
    for (int g = 0; g < 8; g++) {
      float xr[4][4];
#pragma unroll
      for (int r = 0; r < 4; r++)
        *reinterpret_cast<float4*>(xr[r]) = *reinterpret_cast<const float4*>(&Xs[row0 + r][g * 4]);
#pragma unroll
      for (int j = 0; j < 4; j++) {
        const float4 w4 = *reinterpret_cast<const float4*>(&Ws[g * 4 + j][col4]);
#pragma unroll
        for (int r = 0; r < 4; r++) {
          acc[r][0] = fmaf(xr[r][j], w4.x, acc[r][0]);
          acc[r][1] = fmaf(xr[r][j], w4.y, acc[r][1]);
          acc[r][2] = fmaf(xr[r][j], w4.z, acc[r][2]);
          acc[r][3] = fmaf(xr[r][j], w4.w, acc[r][3]);
        }
      }
    }
    __syncthreads();
  }
#pragma unroll
  for (int r = 0; r < 4; r++) {
    int gr = rb + row0 + r;
    if (gr < NN) {
      float4 v = make_float4(acc[r][0], acc[r][1], acc[r][2], acc[r][3]);
      *reinterpret_cast<float4*>(&Ko[(size_t)gr * OC + col4]) = v;
    }
  }
}

// ---------------- merge split-K partials (float4, nsplit-generic) ----------------
__global__ __launch_bounds__(256) void mergeK(const float4* __restrict__ Kp, float4* __restrict__ Kf, int nsplit) {
  size_t i = (size_t)blockIdx.x * 256 + threadIdx.x;
  const size_t n4 = NNOC / 4;
  if (i >= n4) return;
  float4 s = Kp[i];
  for (int ps = 1; ps < nsplit; ps++) {
    float4 v = Kp[(size_t)ps * n4 + i];
    s.x += v.x; s.y += v.y; s.z += v.z; s.w += v.w;
  }
  Kf[i] = s;
}

// ---------------- u1 = U^T@k1, s = U^T@1 (fp64, float4 cols) ----------------
__global__ __launch_bounds__(256) void ut_reduce(const float4* __restrict__ U4, const double* __restrict__ k1,
                                                 double* __restrict__ u1, double* __restrict__ s) {
  int c4 = blockIdx.x * 256 + threadIdx.x;
  if (c4 >= NV) return;
  int r0 = blockIdx.y * 32;
  int r1 = min(NN, r0 + 32);
  double au0 = 0, au1_ = 0, au2 = 0, au3 = 0, as0 = 0, as1 = 0, as2 = 0, as3 = 0;
  for (int r = r0; r < r1; r++) {
    float4 u = U4[(size_t)r * NV + c4];
    double kr = k1[r];
    au0 = fma((double)u.x, kr, au0); au1_ = fma((double)u.y, kr, au1_);
    au2 = fma((double)u.z, kr, au2); au3 = fma((double)u.w, kr, au3);
    as0 += (double)u.x; as1 += (double)u.y; as2 += (double)u.z; as3 += (double)u.w;
  }
  int c = c4 * 4;
  atomicAdd(&u1[c + 0], au0); atomicAdd(&u1[c + 1], au1_);
  atomicAdd(&u1[c + 2], au2); atomicAdd(&u1[c + 3], au3);
  atomicAdd(&s[c + 0], as0);  atomicAdd(&s[c + 1], as1);
  atomicAdd(&s[c + 2], as2);  atomicAdd(&s[c + 3], as3);
}

// ---------------- p = U@(lmbd*u1), q = U@(lmbd*s) (fp64), one wave per row ----------------
__global__ __launch_bounds__(256) void uv_kernel(const float4* __restrict__ U4, const float4* __restrict__ L4,
                                                 const double2* __restrict__ u1d, const double2* __restrict__ sd,
                                                 double* __restrict__ p, double* __restrict__ q) {
  const int t = threadIdx.x;
  const int wave = t >> 6, lane = t & 63;
  const int r = blockIdx.x * 4 + wave;
  if (r >= NN) return;
  const float4* Ur = U4 + (size_t)r * NV;
  double ap = 0.0, aq = 0.0;
  for (int c4 = lane; c4 < NV; c4 += 64) {
    float4 u = Ur[c4];
    float4 lm = L4[c4];
    double2 ua = u1d[c4 * 2], ub = u1d[c4 * 2 + 1];
    double2 sa = sd[c4 * 2],  sb = sd[c4 * 2 + 1];
    ap = fma((double)u.x, (double)lm.x * ua.x, ap);
    ap = fma((double)u.y, (double)lm.y * ua.y, ap);
    ap = fma((double)u.z, (double)lm.z * ub.x, ap);
    ap = fma((double)u.w, (double)lm.w * ub.y, ap);
    aq = fma((double)u.x, (double)lm.x * sa.x, aq);
    aq = fma((double)u.y, (double)lm.y * sa.y, aq);
    aq = fma((double)u.z, (double)lm.z * sb.x, aq);
    aq = fma((double)u.w, (double)lm.w * sb.y, aq);
  }
  for (int o = 32; o; o >>= 1) { ap += __shfl_down(ap, o, 64); aq += __shfl_down(aq, o, 64); }
  if (lane == 0) { p[r] = ap; q[r] = aq; }
}

// ---------------- fused bucket sort of k2 (one block) ----------------
__global__ __launch_bounds__(1024) void sortk2(const double* __restrict__ k2,
                                               double* __restrict__ kvd, int* __restrict__ sortedj,
                                               double* __restrict__ hdr) {
  __shared__ int hist[NB];
  __shared__ int ps[1024];
  __shared__ double rmn[16], rmx[16];
  __shared__ double mn_sh, sc_sh;
  const int t = threadIdx.x, wv = t >> 6, ln = t & 63;

  double mn = 1e300, mx = -1e300;
  for (int j = t; j < NN; j += 1024) { double v = k2[j]; mn = fmin(mn, v); mx = fmax(mx, v); }
  for (int o = 32; o; o >>= 1) { mn = fmin(mn, __shfl_xor(mn, o, 64)); mx = fmax(mx, __shfl_xor(mx, o, 64)); }
  if (ln == 0) { rmn[wv] = mn; rmx[wv] = mx; }
  for (int b = t; b < NB; b += 1024) hist[b] = 0;
  __syncthreads();
  if (t == 0) {
    double amn = rmn[0], amx = rmx[0];
    for (int u = 1; u < 16; u++) { amn = fmin(amn, rmn[u]); amx = fmax(amx, rmx[u]); }
    hdr[0] = amn; hdr[1] = amx;
    mn_sh = amn; sc_sh = NB / fmax(amx - amn, 1e-30);
  }
  __syncthreads();
  const double minv = mn_sh, scale = sc_sh;
  for (int j = t; j < NN; j += 1024) {
    int b = min(NB - 1, max(0, (int)((k2[j] - minv) * scale)));
    atomicAdd(&hist[b], 1);
  }
  __syncthreads();
  int4 v4 = ((const int4*)hist)[t];
  int s = v4.x + v4.y + v4.z + v4.w;
  ps[t] = s;
  __syncthreads();
  for (int d = 1; d < 1024; d <<= 1) {
    int x = (t >= d) ? ps[t - d] : 0;
    __syncthreads();
    ps[t] += x;
    __syncthreads();
  }
  int excl = ps[t] - s;
  hist[4 * t]     = excl;
  hist[4 * t + 1] = excl + v4.x;
  hist[4 * t + 2] = excl + v4.x + v4.y;
  hist[4 * t + 3] = excl + v4.x + v4.y + v4.z;
  __syncthreads();
  for (int j = t; j < NN; j += 1024) {
    double v = k2[j];
    int b = min(NB - 1, max(0, (int)((v - minv) * scale)));
    int pos = atomicAdd(&hist[b], 1);
    kvd[pos] = v;
    sortedj[pos] = j;
  }
}

// Phase 1: walk (margin 21) + weights + SIGNIFICANT-ONLY compaction to global.
__global__ __launch_bounds__(256) void softmax_walk(const unsigned* __restrict__ bm,
                                                    const double* __restrict__ p, const double* __restrict__ q,
                                                    const double* __restrict__ kvd, const int* __restrict__ sortedj,
                                                    const double* __restrict__ hdr,
                                                    short* __restrict__ jsG, float* __restrict__ wG,
                                                    int* __restrict__ nlistG, float* __restrict__ sumwG,
                                                    int maxc) {
  __shared__ float vf[NN];
  __shared__ short js[NN];
  __shared__ int wcnt[4];
  __shared__ double wfv[4], wbnd[4];
  __shared__ float redf[4];

  const int i = blockIdx.x;
  const int t = threadIdx.x;
  const int wv = t >> 6, lane = t & 63;
  const double pi = p[i], qi = q[i];
  const double bw = (hdr[1] - hdr[0]) * (1.0 / NB);
  const double margin = 21.0 + 2.0 * fabs(qi) * bw;   // exp(-21): drops <=2e-6 rel mass
  const unsigned* bmrow = bm + (size_t)i * NW;
  const bool sgn = (qi >= 0.0);
  const unsigned long long ltmask = (1ull << lane) - 1ull;
  int nlist = 0;
  double m_lb = -1e300;

  int coveredA = 0;
  for (int r = 0; r * 256 < NN; r++) {
    int idx = r * 256 + t;
    bool ok = idx < NN;
    double v = 0.0; int j = 0; unsigned a = 0;
    if (ok) {
      int pos = sgn ? (NN - 1 - idx) : idx;
      v = fma(qi, kvd[pos], pi);
      j = sortedj[pos];
      a = (bmrow[j >> 5] >> (j & 31)) & 1u;
    }
    bool isn = ok && a;
    unsigned long long mask = __ballot(isn);
    int wo = __popcll(mask & ltmask);
    double fv = isn ? fabs(v) : -1e300;
    double bnd = ok ? v : 1e300;
    for (int o = 32; o; o >>= 1) {
      fv = fmax(fv, __shfl_xor(fv, o, 64));
      bnd = fmin(bnd, __shfl_xor(bnd, o, 64));
    }
    if (lane == 0) { wcnt[wv] = __popcll(mask); wfv[wv] = fv; wbnd[wv] = bnd; }
    __syncthreads();
    int c0 = wcnt[0], c1 = wcnt[1], c2 = wcnt[2], c3 = wcnt[3];
    int base = nlist + (wv > 0 ? c0 : 0) + (wv > 1 ? c1 : 0) + (wv > 2 ? c2 : 0);
    if (isn) { js[base + wo] = (short)j; vf[base + wo] = (float)v; }
    nlist += c0 + c1 + c2 + c3;
    m_lb = fmax(m_lb, fmax(fmax(wfv[0], wfv[1]), fmax(wfv[2], wfv[3])));
    double rbnd = fmin(fmin(wbnd[0], wbnd[1]), fmin(wbnd[2], wbnd[3]));
    __syncthreads();
    coveredA = min(NN, (r + 1) * 256);
    if (rbnd < m_lb - margin) break;
  }
  const int remB = NN - coveredA;

  for (int r = 0; r * 256 < remB; r++) {
    int idx = r * 256 + t;
    bool ok = idx < remB;
    double v = 0.0; int j = 0; unsigned a = 0;
    if (ok) {
      int pos = sgn ? idx : (NN - 1 - idx);
      v = fma(qi, kvd[pos], pi);
      j = sortedj[pos];
      a = (bmrow[j >> 5] >> (j & 31)) & 1u;
    }
    bool isn = ok && a;
    unsigned long long mask = __ballot(isn);
    int wo = __popcll(mask & ltmask);
    double fv = isn ? fabs(v) : -1e300;
    double bnd = ok ? v : -1e300;
    for (int o = 32; o; o >>= 1) {
      fv = fmax(fv, __shfl_xor(fv, o, 64));
      bnd = fmax(bnd, __shfl_xor(bnd, o, 64));
    }
    if (lane == 0) { wcnt[wv] = __popcll(mask); wfv[wv] = fv; wbnd[wv] = bnd; }
    __syncthreads();
    int c0 = wcnt[0], c1 = wcnt[1], c2 = wcnt[2], c3 = wcnt[3];
    int base = nlist + (wv > 0 ? c0 : 0) + (wv > 1 ? c1 : 0) + (wv > 2 ? c2 : 0);
    if (isn) { js[base + wo] = (short)j; vf[base + wo] = (float)v; }
    nlist += c0 + c1 + c2 + c3;
    m_lb = fmax(m_lb, fmax(fmax(wfv[0], wfv[1]), fmax(wfv[2], wfv[3])));
    double rbnd = fmax(fmax(wbnd[0], wbnd[1]), fmax(wbnd[2], wbnd[3]));
    __syncthreads();
    if (-rbnd < m_lb - margin) break;
  }

  const float fm = (float)m_lb;
  float sw = 0.f;
  for (int c = t; c < nlist; c += 256) {
    float w = __expf(fabsf(vf[c]) - fm);
    vf[c] = w;
    sw += w;
  }
  for (int o = 32; o; o >>= 1) sw += __shfl_xor(sw, o, 64);
  if (lane == 0) redf[wv] = sw;
  __syncthreads();
  const float sumw = (redf[0] + redf[1]) + (redf[2] + redf[3]);

  // compact significant candidates (w > sumw*1e-9): drops <=2.7e-6 rel mass
  const float cut = sumw * 1e-9f;
  short* jd = jsG + (size_t)i * maxc;
  float* wd = wG + (size_t)i * maxc;
  int outn = 0;
  for (int r0 = 0; r0 < nlist; r0 += 256) {
    int c = r0 + t;
    bool keep = (c < nlist) && (vf[c] > cut);
    unsigned long long mask = __ballot(keep);
    int wo = __popcll(mask & ltmask);
    if (lane == 0) wcnt[wv] = __popcll(mask);
    __syncthreads();
    int c0 = wcnt[0], c1 = wcnt[1], c2 = wcnt[2], c3 = wcnt[3];
    int base = outn + (wv > 0 ? c0 : 0) + (wv > 1 ? c1 : 0) + (wv > 2 ? c2 : 0);
    if (keep && base + wo < maxc) { jd[base + wo] = js[c]; wd[base + wo] = vf[c]; }
    outn += c0 + c1 + c2 + c3;
    __syncthreads();
  }
  if (t == 0) { nlistG[i] = min(outn, maxc); sumwG[i] = sumw; }
}

// Phase 2: gather over compacted lists; contiguous slice per (block,group).
__global__ __launch_bounds__(256) void gatherH(const short* __restrict__ jsG, const float* __restrict__ wG,
                                               const int* __restrict__ nlistG,
                                               const float* __restrict__ K, float* __restrict__ Hpart,
                                               int maxc) {
  __shared__ float hp[2][128];
  const int i = blockIdx.x, y = blockIdx.y, G = gridDim.y;
  const int t = threadIdx.x;
  const int ch = t & 127, g = t >> 7;
  const int nl = nlistG[i];
  const int nsl = 2 * G;
  const int len = (nl + nsl - 1) / nsl;
  const int s0 = (y * 2 + g) * len;
  const int s1 = min(nl, s0 + len);
  const short* jl = jsG + (size_t)i * maxc;
  const float* wl = wG + (size_t)i * maxc;
  float acc = 0.f;
  int c = s0;
  for (; c + 1 < s1; c += 2) {
    float w0 = wl[c], w1 = wl[c + 1];
    int j0 = jl[c], j1 = jl[c + 1];
    float k0 = K[(size_t)j0 * OC + ch];
    float k1 = K[(size_t)j1 * OC + ch];
    acc = fmaf(w0, k0, acc);
    acc = fmaf(w1, k1, acc);
  }
  if (c < s1) acc = fmaf(wl[c], K[(size_t)jl[c] * OC + ch], acc);
  hp[g][ch] = acc;
  __syncthreads();
  if (t < 128)
    Hpart[((size_t)i * G + y) * OC + t] = hp[0][t] + hp[1][t];
}

// Phase 3: H = (sum_y Hpart) / sumw
__global__ __launch_bounds__(256) void reduceH(const float* __restrict__ Hpart, const float* __restrict__ sumwG,
                                               float* __restrict__ H, int G) {
  int gid = blockIdx.x * 256 + threadIdx.x;
  if (gid >= (int)NNOC) return;
  int i = gid >> 7, ch = gid & 127;
  float s = 0.f;
  for (int y = 0; y < G; y++) s += Hpart[((size_t)i * G + y) * OC + ch];
  H[gid] = s / sumwG[i];
}

// ---------------- fused fallback for small workspaces ----------------
__global__ __launch_bounds__(256) void softmaxH_fused(const unsigned* __restrict__ bm,
                                                      const double* __restrict__ p, const double* __restrict__ q,
                                                      const double* __restrict__ kvd, const int* __restrict__ sortedj,
                                                      const double* __restrict__ hdr,
                                                      const float* __restrict__ K, float* __restrict__ H) {
  __shared__ float vf[NN];
  __shared__ short js[NN];
  __shared__ float hpart[4][128];
  __shared__ int wcnt[4];
  __shared__ double wfv[4], wbnd[4];
  __shared__ float redf[4];

  const int i = blockIdx.x;
  const int t = threadIdx.x;
  const int wv = t >> 6, lane = t & 63;
  const double pi = p[i], qi = q[i];
  const double bw = (hdr[1] - hdr[0]) * (1.0 / NB);
  const double margin = 21.0 + 2.0 * fabs(qi) * bw;
  const unsigned* bmrow = bm + (size_t)i * NW;
  const bool sgn = (qi >= 0.0);
  const unsigned long long ltmask = (1ull << lane) - 1ull;
  int nlist = 0;
  double m_lb = -1e300;

  int coveredA = 0;
  for (int r = 0; r * 256 < NN; r++) {
    int idx = r * 256 + t;
    bool ok = idx < NN;
    double v = 0.0; int j = 0; unsigned a = 0;
    if (ok) {
      int pos = sgn ? (NN - 1 - idx) : idx;
      v = fma(qi, kvd[pos], pi);
      j = sortedj[pos];
      a = (bmrow[j >> 5] >> (j & 31)) & 1u;
    }
    bool isn = ok && a;
    unsigned long long mask = __ballot(isn);
    int wo = __popcll(mask & ltmask);
    double fv = isn ? fabs(v) : -1e300;
    double bnd = ok ? v : 1e300;
    for (int o = 32; o; o >>= 1) {
      fv = fmax(fv, __shfl_xor(fv, o, 64));
      bnd = fmin(bnd, __shfl_xor(bnd, o, 64));
    }
    if (lane == 0) { wcnt[wv] = __popcll(mask); wfv[wv] = fv; wbnd[wv] = bnd; }
    __syncthreads();
    int c0 = wcnt[0], c1 = wcnt[1], c2 = wcnt[2], c3 = wcnt[3];
    int base = nlist + (wv > 0 ? c0 : 0) + (wv > 1 ? c1 : 0) + (wv > 2 ? c2 : 0);
    if (isn) { js[base + wo] = (short)j; vf[base + wo] = (float)v; }
    nlist += c0 + c1 + c2 + c3;
    m_lb = fmax(m_lb, fmax(fmax(wfv[0], wfv[1]), fmax(wfv[2], wfv[3])));
    double rbnd = fmin(fmin(wbnd[0], wbnd[1]), fmin(wbnd[2], wbnd[3]));
    __syncthreads();
    coveredA = min(NN, (r + 1) * 256);
    if (rbnd < m_lb - margin) break;
  }
  const int remB = NN - coveredA;

  for (int r = 0; r * 256 < remB; r++) {
    int idx = r * 256 + t;
    bool ok = idx < remB;
    double v = 0.0; int j = 0; unsigned a = 0;
    if (ok) {
      int pos = sgn ? idx : (NN - 1 - idx);
      v = fma(qi, kvd[pos], pi);
      j = sortedj[pos];
      a = (bmrow[j >> 5] >> (j & 31)) & 1u;
    }
    bool isn = ok && a;
    unsigned long long mask = __ballot(isn);
    int wo = __popcll(mask & ltmask);
    double fv = isn ? fabs(v) : -1e300;
    double bnd = ok ? v : -1e300;
    for (int o = 32; o; o >>= 1) {
      fv = fmax(fv, __shfl_xor(fv, o, 64));
      bnd = fmax(bnd, __shfl_xor(bnd, o, 64));
    }
    if (lane == 0) { wcnt[wv] = __popcll(mask); wfv[wv] = fv; wbnd[wv] = bnd; }
    __syncthreads();
    int c0 = wcnt[0], c1 = wcnt[1], c2 = wcnt[2], c3 = wcnt[3];
    int base = nlist + (wv > 0 ? c0 : 0) + (wv > 1 ? c1 : 0) + (wv > 2 ? c2 : 0);
    if (isn) { js[base + wo] = (short)j; vf[base + wo] = (float)v; }
    nlist += c0 + c1 + c2 + c3;
    m_lb = fmax(m_lb, fmax(fmax(wfv[0], wfv[1]), fmax(wfv[2], wfv[3])));
    double rbnd = fmax(fmax(wbnd[0], wbnd[1]), fmax(wbnd[2], wbnd[3]));
    __syncthreads();
    if (-rbnd < m_lb - margin) break;
  }

  const float fm = (float)m_lb;
  float sw = 0.f;
  for (int c = t; c < nlist; c += 256) {
    float w = __expf(fabsf(vf[c]) - fm);
    vf[c] = w;
    sw += w;
  }
  for (int o = 32; o; o >>= 1) sw += __shfl_xor(sw, o, 64);
  if (lane == 0) redf[wv] = sw;
  __syncthreads();
  const float sumw = (redf[0] + redf[1]) + (redf[2] + redf[3]);

  const int ch = t & 63, g = t >> 6;
  float a0 = 0.f, a1 = 0.f;
  int c = g;
  for (; c + 4 < nlist; c += 8) {
    float w0 = vf[c], w1 = vf[c + 4];
    const float* K0 = K + (size_t)js[c] * OC;
    const float* K1 = K + (size_t)js[c + 4] * OC;
    float k00 = K0[ch], k01 = K0[64 + ch];
    float k10 = K1[ch], k11 = K1[64 + ch];
    a0 = fmaf(w0, k00, a0); a1 = fmaf(w0, k01, a1);
    a0 = fmaf(w1, k10, a0); a1 = fmaf(w1, k11, a1);
  }
  for (; c < nlist; c += 4) {
    float w = vf[c];
    const float* Kr = K + (size_t)js[c] * OC;
    a0 = fmaf(w, Kr[ch], a0);
    a1 = fmaf(w, Kr[64 + ch], a1);
  }
  hpart[g][ch] = a0;
  hpart[g][64 + ch] = a1;
  __syncthreads();
  if (t < 128) {
    float hv = (hpart[0][t] + hpart[1][t]) + (hpart[2][t] + hpart[3][t]);
    H[(size_t)i * OC + t] = hv / sumw;
  }
}

extern "C" void kernel_launch(void* const* d_in, const int* in_sizes, int n_in,
                              void* d_out, int out_size, void* d_ws, size_t ws_size,
                              hipStream_t stream) {
  const float* X    = (const float*)d_in[0];
  const int*   A    = (const int*)d_in[1];
  const float* U    = (const float*)d_in[2];
  const float* W    = (const float*)d_in[3];
  const float* a1   = (const float*)d_in[4];
  const float* a2   = (const float*)d_in[5];
  const float* lmbd = (const float*)d_in[6];
  float* H = (float*)d_out;

  const size_t wt_bytes  = (size_t)IC * OC * 4;
  const size_t bm_bytes  = (size_t)NN * NW * 4;
  const size_t dbl_bytes = (size_t)(7 * NN + 2 * IC + 2) * 8;

  // config cascade: (nsplit, G, MAXC); G=0 => fused fallback
  const int cfgs[10][3] = {{16,4,2048},{8,4,2048},{8,4,1536},{4,4,1024},{2,4,1024},
                           {8,0,0},{4,0,0},{2,0,0},{1,0,0},{1,0,0}};
  int nsplit = 1, G = 0, MAXC = 0;
  for (int ci = 0; ci < 10; ci++) {
    int ns = cfgs[ci][0], g = cfgs[ci][1], mc = cfgs[ci][2];
    size_t need = (size_t)(ns > 1 ? ns + 1 : 1) * NNOC * 4 + wt_bytes + dbl_bytes +
                  (size_t)NN * 4 + bm_bytes + 1024;
    if (g > 0)
      need += (size_t)NN * mc * 2 + (size_t)NN * mc * 4 +
              (size_t)NN * g * OC * 4 + (size_t)NN * 8;
    if (need <= ws_size) { nsplit = ns; G = g; MAXC = mc; break; }
  }

  char* base = (char*)d_ws;
  float* Kp = (float*)base;
  float* Kf = (nsplit > 1) ? (float*)(base + (size_t)nsplit * NNOC * 4) : Kp;
  size_t off = (size_t)(nsplit > 1 ? nsplit + 1 : 1) * NNOC * 4;
  float* Wt = (float*)(base + off);            off += wt_bytes;
  double* dbl = (double*)(base + off);         off += dbl_bytes;
  double* k1  = dbl;
  double* k2  = k1 + NN;
  double* u1  = k2 + NN;
  double* sC  = u1 + NN;
  double* p   = sC + NN;
  double* q   = p  + NN;
  double* kvd = q  + NN;
  double* w1  = kvd + NN;
  double* w2  = w1 + IC;
  double* hdr = w2 + IC;
  int* sortedj = (int*)(base + off);           off += (size_t)NN * 4;
  unsigned* bm = (unsigned*)(base + off);      off += bm_bytes;
  float* wG = nullptr; float* Hpart = nullptr; float* sumwG = nullptr;
  int* nlistG = nullptr; short* jsG = nullptr;
  if (G > 0) {
    wG     = (float*)(base + off);             off += (size_t)NN * MAXC * 4;
    Hpart  = (float*)(base + off);             off += (size_t)NN * G * OC * 4;
    sumwG  = (float*)(base + off);             off += (size_t)NN * 4;
    nlistG = (int*)(base + off);               off += (size_t)NN * 4;
    jsG    = (short*)(base + off);             off += (size_t)NN * MAXC * 2;
  }

  const int chunk = (IC + nsplit - 1) / nsplit;

  bitmapA_zero<<<(NN * NW + 255) / 256, 256, 0, stream>>>(A, bm, u1, 2 * NN);
  transposeW<<<dim3((IC + 31) / 32, OC / 32), 256, 0, stream>>>(W, Wt);
  wvec_t<<<(IC + 3) / 4, 256, 0, stream>>>(Wt, a1, a2, w1, w2);
  xw<<<NN / 4, 256, 0, stream>>>(X, w1, w2, k1, k2);
  gemmK<<<dim3((NN + 31) / 32, nsplit), 256, 0, stream>>>(X, Wt, Kp, chunk);
  if (nsplit > 1)
    mergeK<<<(int)((NNOC / 4 + 255) / 256), 256, 0, stream>>>((const float4*)Kp, (float4*)Kf, nsplit);
  ut_reduce<<<dim3((NV + 255) / 256, (NN + 31) / 32), 256, 0, stream>>>((const float4*)U, k1, u1, sC);
  uv_kernel<<<NN / 4, 256, 0, stream>>>((const float4*)U, (const float4*)lmbd,
                                        (const double2*)u1, (const double2*)sC, p, q);
  sortk2<<<1, 1024, 0, stream>>>(k2, kvd, sortedj, hdr);
  if (G > 0) {
    softmax_walk<<<NN, 256, 0, stream>>>(bm, p, q, kvd, sortedj, hdr, jsG, wG, nlistG, sumwG, MAXC);
    gatherH<<<dim3(NN, G), 256, 0, stream>>>(jsG, wG, nlistG, Kf, Hpart, MAXC);
    reduceH<<<(int)((NNOC + 255) / 256), 256, 0, stream>>>(Hpart, sumwG, H, G);
  } else {
    softmaxH_fused<<<NN, 256, 0, stream>>>(bm, p, q, kvd, sortedj, hdr, Kf, H);
  }
}

// Round 12
// 250.322 us; speedup vs baseline: 1.1470x; 1.1036x over previous
//
#include <hip/hip_runtime.h>
#include <math.h>

#define NN 2708
#define IC 1433
#define OC 128
#define NV (NN / 4)          // 677 float4/int4 per row (exact)
#define NNOC ((size_t)NN * OC)
#define NB 4096              // sort buckets
#define NW 85                // ceil(NN/32) bitmap words per row

// ---------------- bitmap of A (bit j of word w = A[i][32w+j]!=0) + zero u1/sC ----------------
__global__ __launch_bounds__(256) void bitmapA_zero(const int* __restrict__ A, unsigned* __restrict__ bm,
                                                    double* __restrict__ zd, int nzd) {
  int gid = blockIdx.x * 256 + threadIdx.x;
  if (gid < nzd) zd[gid] = 0.0;
  const int total = NN * NW;
  if (gid >= total) return;
  int i = gid / NW, w = gid - i * NW;
  const int* Ar = A + (size_t)i * NN + w * 32;
  unsigned word = 0;
  if (w < NW - 1) {
    const int4* a4 = (const int4*)Ar;
#pragma unroll
    for (int u = 0; u < 8; u++) {
      int4 a = a4[u];
      word |= (a.x != 0 ? 1u : 0u) << (4 * u);
      word |= (a.y != 0 ? 1u : 0u) << (4 * u + 1);
      word |= (a.z != 0 ? 1u : 0u) << (4 * u + 2);
      word |= (a.w != 0 ? 1u : 0u) << (4 * u + 3);
    }
  } else {
    const int nbits = NN - w * 32;
    for (int b = 0; b < nbits; b++) word |= (Ar[b] != 0 ? 1u : 0u) << b;
  }
  bm[(size_t)i * NW + w] = word;
}

// ---------------- Wt[k][o] = W[o][k] (32x32 LDS tile transpose) ----------------
__global__ __launch_bounds__(256) void transposeW(const float* __restrict__ W, float* __restrict__ Wt) {
  __shared__ float tile[32][33];
  const int t = threadIdx.x;
  const int k0 = blockIdx.x * 32, o0 = blockIdx.y * 32;
#pragma unroll
  for (int it = 0; it < 4; it++) {
    int ro = (t >> 5) + it * 8;
    int k  = k0 + (t & 31);
    tile[ro][t & 31] = (k < IC) ? W[(size_t)(o0 + ro) * IC + k] : 0.f;
  }
  __syncthreads();
#pragma unroll
  for (int it = 0; it < 4; it++) {
    int rk = (t >> 5) + it * 8;
    int k  = k0 + rk;
    if (k < IC) Wt[(size_t)k * OC + o0 + (t & 31)] = tile[t & 31][rk];
  }
}

// ---------------- w1 = W^T a1, w2 = W^T a2 from Wt (fp64, one wave per column c) ----------------
__global__ __launch_bounds__(256) void wvec_t(const float* __restrict__ Wt, const float* __restrict__ a1,
                                              const float* __restrict__ a2,
                                              double* __restrict__ w1, double* __restrict__ w2) {
  const int t = threadIdx.x;
  const int wv = t >> 6, lane = t & 63;
  const int c = blockIdx.x * 4 + wv;
  if (c >= IC) return;
  const float* Wr = Wt + (size_t)c * OC;
  double wa = (double)Wr[lane], wb = (double)Wr[64 + lane];
  double s1 = fma(wa, (double)a1[lane], wb * (double)a1[64 + lane]);
  double s2 = fma(wa, (double)a2[lane], wb * (double)a2[64 + lane]);
  for (int o = 32; o; o >>= 1) { s1 += __shfl_down(s1, o, 64); s2 += __shfl_down(s2, o, 64); }
  if (lane == 0) { w1[c] = s1; w2[c] = s2; }
}

// ---------------- k1 = X@w1, k2 = X@w2 (fp64), one wave per row ----------------
__global__ __launch_bounds__(256) void xw(const float* __restrict__ X, const double* __restrict__ w1,
                                          const double* __restrict__ w2,
                                          double* __restrict__ k1, double* __restrict__ k2) {
  __shared__ double w1s[IC];
  __shared__ double w2s[IC];
  const int t = threadIdx.x;
  for (int c = t; c < IC; c += 256) { w1s[c] = w1[c]; w2s[c] = w2[c]; }
  __syncthreads();
  const int wave = t >> 6, lane = t & 63;
  const int i = blockIdx.x * 4 + wave;
  if (i >= NN) return;
  const float* Xi = X + (size_t)i * IC;
  double s1 = 0.0, s2 = 0.0;
  for (int c = lane; c < IC; c += 64) {
    double x = (double)Xi[c];
    s1 = fma(x, w1s[c], s1);
    s2 = fma(x, w2s[c], s2);
  }
  for (int o = 32; o; o >>= 1) { s1 += __shfl_down(s1, o, 64); s2 += __shfl_down(s2, o, 64); }
  if (lane == 0) { k1[i] = s1; k2[i] = s2; }
}

// ---------------- K partials: Kp[split] = X @ Wt over k-chunk (fp32, conflict-free LDS) ----------------
__global__ __launch_bounds__(256) void gemmK(const float* __restrict__ X, const float* __restrict__ Wt,
                                             float* __restrict__ Kp, int chunk) {
  __shared__ float Xs[32][36];
  __shared__ float Ws[32][132];
  const int t  = threadIdx.x;
  const int rb = blockIdx.x * 32;
  const int ks = blockIdx.y * chunk;
  const int ke = min(IC, ks + chunk);
  float* __restrict__ Ko = Kp + (size_t)blockIdx.y * NNOC;
  const int row0 = (t >> 5) * 4;
  const int col4 = (t & 31) * 4;
  float acc[4][4];
#pragma unroll
  for (int r = 0; r < 4; r++)
#pragma unroll
    for (int c = 0; c < 4; c++) acc[r][c] = 0.f;

  for (int kb = ks; kb < ke; kb += 32) {
#pragma unroll
    for (int it = 0; it < 4; it++) {
      int idx = t + it * 256;
      int r = idx >> 5, c = idx & 31;
      int gr = rb + r, gc = kb + c;
      Xs[r][c] = (gr < NN && gc < ke) ? X[(size_t)gr * IC + gc] : 0.f;
    }
#pragma unroll
    for (int it = 0; it < 4; it++) {
      int idx4 = t + it * 256;
      int k = idx4 >> 5, cg = (idx4 & 31) * 4;
      int gk = kb + k;
      float4 v = make_float4(0.f, 0.f, 0.f, 0.f);
      if (gk < ke) v = *reinterpret_cast<const float4*>(&Wt[(size_t)gk * OC + cg]);
      *reinterpret_cast<float4*>(&Ws[k][cg]) = v;
    }
    __syncthreads();
#pragma unroll
    for (int g = 0; g < 8; g++) {
      float xr[4][4];
#pragma unroll
      for (int r = 0; r < 4; r++)
        *reinterpret_cast<float4*>(xr[r]) = *reinterpret_cast<const float4*>(&Xs[row0 + r][g * 4]);
#pragma unroll
      for (int j = 0; j < 4; j++) {
        const float4 w4 = *reinterpret_cast<const float4*>(&Ws[g * 4 + j][col4]);
#pragma unroll
        for (int r = 0; r < 4; r++) {
          acc[r][0] = fmaf(xr[r][j], w4.x, acc[r][0]);
          acc[r][1] = fmaf(xr[r][j], w4.y, acc[r][1]);
          acc[r][2] = fmaf(xr[r][j], w4.z, acc[r][2]);
          acc[r][3] = fmaf(xr[r][j], w4.w, acc[r][3]);
        }
      }
    }
    __syncthreads();
  }
#pragma unroll
  for (int r = 0; r < 4; r++) {
    int gr = rb + row0 + r;
    if (gr < NN) {
      float4 v = make_float4(acc[r][0], acc[r][1], acc[r][2], acc[r][3]);
      *reinterpret_cast<float4*>(&Ko[(size_t)gr * OC + col4]) = v;
    }
  }
}

// ---------------- merge split-K partials (float4, nsplit-generic) ----------------
__global__ __launch_bounds__(256) void mergeK(const float4* __restrict__ Kp, float4* __restrict__ Kf, int nsplit) {
  size_t i = (size_t)blockIdx.x * 256 + threadIdx.x;
  const size_t n4 = NNOC / 4;
  if (i >= n4) return;
  float4 s = Kp[i];
  for (int ps = 1; ps < nsplit; ps++) {
    float4 v = Kp[(size_t)ps * n4 + i];
    s.x += v.x; s.y += v.y; s.z += v.z; s.w += v.w;
  }
  Kf[i] = s;
}

// ---------------- u1 = U^T@k1, s = U^T@1 (fp64, float4 cols) ----------------
__global__ __launch_bounds__(256) void ut_reduce(const float4* __restrict__ U4, const double* __restrict__ k1,
                                                 double* __restrict__ u1, double* __restrict__ s) {
  int c4 = blockIdx.x * 256 + threadIdx.x;
  if (c4 >= NV) return;
  int r0 = blockIdx.y * 32;
  int r1 = min(NN, r0 + 32);
  double au0 = 0, au1_ = 0, au2 = 0, au3 = 0, as0 = 0, as1 = 0, as2 = 0, as3 = 0;
  for (int r = r0; r < r1; r++) {
    float4 u = U4[(size_t)r * NV + c4];
    double kr = k1[r];
    au0 = fma((double)u.x, kr, au0); au1_ = fma((double)u.y, kr, au1_);
    au2 = fma((double)u.z, kr, au2); au3 = fma((double)u.w, kr, au3);
    as0 += (double)u.x; as1 += (double)u.y; as2 += (double)u.z; as3 += (double)u.w;
  }
  int c = c4 * 4;
  atomicAdd(&u1[c + 0], au0); atomicAdd(&u1[c + 1], au1_);
  atomicAdd(&u1[c + 2], au2); atomicAdd(&u1[c + 3], au3);
  atomicAdd(&s[c + 0], as0);  atomicAdd(&s[c + 1], as1);
  atomicAdd(&s[c + 2], as2);  atomicAdd(&s[c + 3], as3);
}

// ---------------- p = U@(lmbd*u1), q = U@(lmbd*s) (fp64), one wave per row ----------------
__global__ __launch_bounds__(256) void uv_kernel(const float4* __restrict__ U4, const float4* __restrict__ L4,
                                                 const double2* __restrict__ u1d, const double2* __restrict__ sd,
                                                 double* __restrict__ p, double* __restrict__ q) {
  const int t = threadIdx.x;
  const int wave = t >> 6, lane = t & 63;
  const int r = blockIdx.x * 4 + wave;
  if (r >= NN) return;
  const float4* Ur = U4 + (size_t)r * NV;
  double ap = 0.0, aq = 0.0;
  for (int c4 = lane; c4 < NV; c4 += 64) {
    float4 u = Ur[c4];
    float4 lm = L4[c4];
    double2 ua = u1d[c4 * 2], ub = u1d[c4 * 2 + 1];
    double2 sa = sd[c4 * 2],  sb = sd[c4 * 2 + 1];
    ap = fma((double)u.x, (double)lm.x * ua.x, ap);
    ap = fma((double)u.y, (double)lm.y * ua.y, ap);
    ap = fma((double)u.z, (double)lm.z * ub.x, ap);
    ap = fma((double)u.w, (double)lm.w * ub.y, ap);
    aq = fma((double)u.x, (double)lm.x * sa.x, aq);
    aq = fma((double)u.y, (double)lm.y * sa.y, aq);
    aq = fma((double)u.z, (double)lm.z * sb.x, aq);
    aq = fma((double)u.w, (double)lm.w * sb.y, aq);
  }
  for (int o = 32; o; o >>= 1) { ap += __shfl_down(ap, o, 64); aq += __shfl_down(aq, o, 64); }
  if (lane == 0) { p[r] = ap; q[r] = aq; }
}

// ---------------- fused bucket sort of k2 (one block) ----------------
__global__ __launch_bounds__(1024) void sortk2(const double* __restrict__ k2,
                                               double* __restrict__ kvd, int* __restrict__ sortedj,
                                               double* __restrict__ hdr) {
  __shared__ int hist[NB];
  __shared__ int ps[1024];
  __shared__ double rmn[16], rmx[16];
  __shared__ double mn_sh, sc_sh;
  const int t = threadIdx.x, wv = t >> 6, ln = t & 63;

  double mn = 1e300, mx = -1e300;
  for (int j = t; j < NN; j += 1024) { double v = k2[j]; mn = fmin(mn, v); mx = fmax(mx, v); }
  for (int o = 32; o; o >>= 1) { mn = fmin(mn, __shfl_xor(mn, o, 64)); mx = fmax(mx, __shfl_xor(mx, o, 64)); }
  if (ln == 0) { rmn[wv] = mn; rmx[wv] = mx; }
  for (int b = t; b < NB; b += 1024) hist[b] = 0;
  __syncthreads();
  if (t == 0) {
    double amn = rmn[0], amx = rmx[0];
    for (int u = 1; u < 16; u++) { amn = fmin(amn, rmn[u]); amx = fmax(amx, rmx[u]); }
    hdr[0] = amn; hdr[1] = amx;
    mn_sh = amn; sc_sh = NB / fmax(amx - amn, 1e-30);
  }
  __syncthreads();
  const double minv = mn_sh, scale = sc_sh;
  for (int j = t; j < NN; j += 1024) {
    int b = min(NB - 1, max(0, (int)((k2[j] - minv) * scale)));
    atomicAdd(&hist[b], 1);
  }
  __syncthreads();
  int4 v4 = ((const int4*)hist)[t];
  int s = v4.x + v4.y + v4.z + v4.w;
  ps[t] = s;
  __syncthreads();
  for (int d = 1; d < 1024; d <<= 1) {
    int x = (t >= d) ? ps[t - d] : 0;
    __syncthreads();
    ps[t] += x;
    __syncthreads();
  }
  int excl = ps[t] - s;
  hist[4 * t]     = excl;
  hist[4 * t + 1] = excl + v4.x;
  hist[4 * t + 2] = excl + v4.x + v4.y;
  hist[4 * t + 3] = excl + v4.x + v4.y + v4.z;
  __syncthreads();
  for (int j = t; j < NN; j += 1024) {
    double v = k2[j];
    int b = min(NB - 1, max(0, (int)((v - minv) * scale)));
    int pos = atomicAdd(&hist[b], 1);
    kvd[pos] = v;
    sortedj[pos] = j;
  }
}

// Phase 1: walk (margin 21) + weights + SIGNIFICANT-ONLY compaction to global.
__global__ __launch_bounds__(256) void softmax_walk(const unsigned* __restrict__ bm,
                                                    const double* __restrict__ p, const double* __restrict__ q,
                                                    const double* __restrict__ kvd, const int* __restrict__ sortedj,
                                                    const double* __restrict__ hdr,
                                                    short* __restrict__ jsG, float* __restrict__ wG,
                                                    int* __restrict__ nlistG, float* __restrict__ sumwG,
                                                    int maxc) {
  __shared__ float vf[NN];
  __shared__ short js[NN];
  __shared__ int wcnt[4];
  __shared__ double wfv[4], wbnd[4];
  __shared__ float redf[4];

  const int i = blockIdx.x;
  const int t = threadIdx.x;
  const int wv = t >> 6, lane = t & 63;
  const double pi = p[i], qi = q[i];
  const double bw = (hdr[1] - hdr[0]) * (1.0 / NB);
  const double margin = 21.0 + 2.0 * fabs(qi) * bw;   // exp(-21): drops <=2e-6 rel mass
  const unsigned* bmrow = bm + (size_t)i * NW;
  const bool sgn = (qi >= 0.0);
  const unsigned long long ltmask = (1ull << lane) - 1ull;
  int nlist = 0;
  double m_lb = -1e300;

  int coveredA = 0;
  for (int r = 0; r * 256 < NN; r++) {
    int idx = r * 256 + t;
    bool ok = idx < NN;
    double v = 0.0; int j = 0; unsigned a = 0;
    if (ok) {
      int pos = sgn ? (NN - 1 - idx) : idx;
      v = fma(qi, kvd[pos], pi);
      j = sortedj[pos];
      a = (bmrow[j >> 5] >> (j & 31)) & 1u;
    }
    bool isn = ok && a;
    unsigned long long mask = __ballot(isn);
    int wo = __popcll(mask & ltmask);
    double fv = isn ? fabs(v) : -1e300;
    double bnd = ok ? v : 1e300;
    for (int o = 32; o; o >>= 1) {
      fv = fmax(fv, __shfl_xor(fv, o, 64));
      bnd = fmin(bnd, __shfl_xor(bnd, o, 64));
    }
    if (lane == 0) { wcnt[wv] = __popcll(mask); wfv[wv] = fv; wbnd[wv] = bnd; }
    __syncthreads();
    int c0 = wcnt[0], c1 = wcnt[1], c2 = wcnt[2], c3 = wcnt[3];
    int base = nlist + (wv > 0 ? c0 : 0) + (wv > 1 ? c1 : 0) + (wv > 2 ? c2 : 0);
    if (isn) { js[base + wo] = (short)j; vf[base + wo] = (float)v; }
    nlist += c0 + c1 + c2 + c3;
    m_lb = fmax(m_lb, fmax(fmax(wfv[0], wfv[1]), fmax(wfv[2], wfv[3])));
    double rbnd = fmin(fmin(wbnd[0], wbnd[1]), fmin(wbnd[2], wbnd[3]));
    __syncthreads();
    coveredA = min(NN, (r + 1) * 256);
    if (rbnd < m_lb - margin) break;
  }
  const int remB = NN - coveredA;

  for (int r = 0; r * 256 < remB; r++) {
    int idx = r * 256 + t;
    bool ok = idx < remB;
    double v = 0.0; int j = 0; unsigned a = 0;
    if (ok) {
      int pos = sgn ? idx : (NN - 1 - idx);
      v = fma(qi, kvd[pos], pi);
      j = sortedj[pos];
      a = (bmrow[j >> 5] >> (j & 31)) & 1u;
    }
    bool isn = ok && a;
    unsigned long long mask = __ballot(isn);
    int wo = __popcll(mask & ltmask);
    double fv = isn ? fabs(v) : -1e300;
    double bnd = ok ? v : -1e300;
    for (int o = 32; o; o >>= 1) {
      fv = fmax(fv, __shfl_xor(fv, o, 64));
      bnd = fmax(bnd, __shfl_xor(bnd, o, 64));
    }
    if (lane == 0) { wcnt[wv] = __popcll(mask); wfv[wv] = fv; wbnd[wv] = bnd; }
    __syncthreads();
    int c0 = wcnt[0], c1 = wcnt[1], c2 = wcnt[2], c3 = wcnt[3];
    int base = nlist + (wv > 0 ? c0 : 0) + (wv > 1 ? c1 : 0) + (wv > 2 ? c2 : 0);
    if (isn) { js[base + wo] = (short)j; vf[base + wo] = (float)v; }
    nlist += c0 + c1 + c2 + c3;
    m_lb = fmax(m_lb, fmax(fmax(wfv[0], wfv[1]), fmax(wfv[2], wfv[3])));
    double rbnd = fmax(fmax(wbnd[0], wbnd[1]), fmax(wbnd[2], wbnd[3]));
    __syncthreads();
    if (-rbnd < m_lb - margin) break;
  }

  const float fm = (float)m_lb;
  float sw = 0.f;
  for (int c = t; c < nlist; c += 256) {
    float w = __expf(fabsf(vf[c]) - fm);
    vf[c] = w;
    sw += w;
  }
  for (int o = 32; o; o >>= 1) sw += __shfl_xor(sw, o, 64);
  if (lane == 0) redf[wv] = sw;
  __syncthreads();
  const float sumw = (redf[0] + redf[1]) + (redf[2] + redf[3]);

  // compact significant candidates (w > sumw*1e-9): drops <=2.7e-6 rel mass
  const float cut = sumw * 1e-9f;
  short* jd = jsG + (size_t)i * maxc;
  float* wd = wG + (size_t)i * maxc;
  int outn = 0;
  for (int r0 = 0; r0 < nlist; r0 += 256) {
    int c = r0 + t;
    bool keep = (c < nlist) && (vf[c] > cut);
    unsigned long long mask = __ballot(keep);
    int wo = __popcll(mask & ltmask);
    if (lane == 0) wcnt[wv] = __popcll(mask);
    __syncthreads();
    int c0 = wcnt[0], c1 = wcnt[1], c2 = wcnt[2], c3 = wcnt[3];
    int base = outn + (wv > 0 ? c0 : 0) + (wv > 1 ? c1 : 0) + (wv > 2 ? c2 : 0);
    if (keep && base + wo < maxc) { jd[base + wo] = js[c]; wd[base + wo] = vf[c]; }
    outn += c0 + c1 + c2 + c3;
    __syncthreads();
  }
  if (t == 0) { nlistG[i] = min(outn, maxc); sumwG[i] = sumw; }
}

// Phase 2: gather over compacted lists; grid (NN, G=16); 32 contiguous slices/row; 4x unroll (MLP).
__global__ __launch_bounds__(256) void gatherH(const short* __restrict__ jsG, const float* __restrict__ wG,
                                               const int* __restrict__ nlistG,
                                               const float* __restrict__ K, float* __restrict__ Hpart,
                                               int maxc) {
  __shared__ float hp[2][128];
  const int i = blockIdx.x, y = blockIdx.y, G = gridDim.y;
  const int t = threadIdx.x;
  const int ch = t & 127, g = t >> 7;
  const int nl = nlistG[i];
  const int nsl = 2 * G;
  const int len = (nl + nsl - 1) / nsl;
  const int s0 = min(nl, (y * 2 + g) * len);
  const int s1 = min(nl, s0 + len);
  const short* jl = jsG + (size_t)i * maxc;
  const float* wl = wG + (size_t)i * maxc;
  float acc = 0.f;
  int c = s0;
  for (; c + 3 < s1; c += 4) {              // 4 independent K loads in flight
    float w0 = wl[c], w1 = wl[c + 1], w2 = wl[c + 2], w3 = wl[c + 3];
    int j0 = jl[c], j1 = jl[c + 1], j2 = jl[c + 2], j3 = jl[c + 3];
    float k0 = K[(size_t)j0 * OC + ch];
    float k1 = K[(size_t)j1 * OC + ch];
    float k2v = K[(size_t)j2 * OC + ch];
    float k3 = K[(size_t)j3 * OC + ch];
    acc = fmaf(w0, k0, acc); acc = fmaf(w1, k1, acc);
    acc = fmaf(w2, k2v, acc); acc = fmaf(w3, k3, acc);
  }
  for (; c < s1; c++)
    acc = fmaf(wl[c], K[(size_t)jl[c] * OC + ch], acc);
  hp[g][ch] = acc;
  __syncthreads();
  if (t < 128)
    Hpart[((size_t)i * G + y) * OC + t] = hp[0][t] + hp[1][t];
}

// Phase 3: H = (sum_y Hpart) / sumw
__global__ __launch_bounds__(256) void reduceH(const float* __restrict__ Hpart, const float* __restrict__ sumwG,
                                               float* __restrict__ H, int G) {
  int gid = blockIdx.x * 256 + threadIdx.x;
  if (gid >= (int)NNOC) return;
  int i = gid >> 7, ch = gid & 127;
  float s = 0.f;
  for (int y = 0; y < G; y++) s += Hpart[((size_t)i * G + y) * OC + ch];
  H[gid] = s / sumwG[i];
}

// ---------------- fused fallback for small workspaces ----------------
__global__ __launch_bounds__(256) void softmaxH_fused(const unsigned* __restrict__ bm,
                                                      const double* __restrict__ p, const double* __restrict__ q,
                                                      const double* __restrict__ kvd, const int* __restrict__ sortedj,
                                                      const double* __restrict__ hdr,
                                                      const float* __restrict__ K, float* __restrict__ H) {
  __shared__ float vf[NN];
  __shared__ short js[NN];
  __shared__ float hpart[4][128];
  __shared__ int wcnt[4];
  __shared__ double wfv[4], wbnd[4];
  __shared__ float redf[4];

  const int i = blockIdx.x;
  const int t = threadIdx.x;
  const int wv = t >> 6, lane = t & 63;
  const double pi = p[i], qi = q[i];
  const double bw = (hdr[1] - hdr[0]) * (1.0 / NB);
  const double margin = 21.0 + 2.0 * fabs(qi) * bw;
  const unsigned* bmrow = bm + (size_t)i * NW;
  const bool sgn = (qi >= 0.0);
  const unsigned long long ltmask = (1ull << lane) - 1ull;
  int nlist = 0;
  double m_lb = -1e300;

  int coveredA = 0;
  for (int r = 0; r * 256 < NN; r++) {
    int idx = r * 256 + t;
    bool ok = idx < NN;
    double v = 0.0; int j = 0; unsigned a = 0;
    if (ok) {
      int pos = sgn ? (NN - 1 - idx) : idx;
      v = fma(qi, kvd[pos], pi);
      j = sortedj[pos];
      a = (bmrow[j >> 5] >> (j & 31)) & 1u;
    }
    bool isn = ok && a;
    unsigned long long mask = __ballot(isn);
    int wo = __popcll(mask & ltmask);
    double fv = isn ? fabs(v) : -1e300;
    double bnd = ok ? v : 1e300;
    for (int o = 32; o; o >>= 1) {
      fv = fmax(fv, __shfl_xor(fv, o, 64));
      bnd = fmin(bnd, __shfl_xor(bnd, o, 64));
    }
    if (lane == 0) { wcnt[wv] = __popcll(mask); wfv[wv] = fv; wbnd[wv] = bnd; }
    __syncthreads();
    int c0 = wcnt[0], c1 = wcnt[1], c2 = wcnt[2], c3 = wcnt[3];
    int base = nlist + (wv > 0 ? c0 : 0) + (wv > 1 ? c1 : 0) + (wv > 2 ? c2 : 0);
    if (isn) { js[base + wo] = (short)j; vf[base + wo] = (float)v; }
    nlist += c0 + c1 + c2 + c3;
    m_lb = fmax(m_lb, fmax(fmax(wfv[0], wfv[1]), fmax(wfv[2], wfv[3])));
    double rbnd = fmin(fmin(wbnd[0], wbnd[1]), fmin(wbnd[2], wbnd[3]));
    __syncthreads();
    coveredA = min(NN, (r + 1) * 256);
    if (rbnd < m_lb - margin) break;
  }
  const int remB = NN - coveredA;

  for (int r = 0; r * 256 < remB; r++) {
    int idx = r * 256 + t;
    bool ok = idx < remB;
    double v = 0.0; int j = 0; unsigned a = 0;
    if (ok) {
      int pos = sgn ? idx : (NN - 1 - idx);
      v = fma(qi, kvd[pos], pi);
      j = sortedj[pos];
      a = (bmrow[j >> 5] >> (j & 31)) & 1u;
    }
    bool isn = ok && a;
    unsigned long long mask = __ballot(isn);
    int wo = __popcll(mask & ltmask);
    double fv = isn ? fabs(v) : -1e300;
    double bnd = ok ? v : -1e300;
    for (int o = 32; o; o >>= 1) {
      fv = fmax(fv, __shfl_xor(fv, o, 64));
      bnd = fmax(bnd, __shfl_xor(bnd, o, 64));
    }
    if (lane == 0) { wcnt[wv] = __popcll(mask); wfv[wv] = fv; wbnd[wv] = bnd; }
    __syncthreads();
    int c0 = wcnt[0], c1 = wcnt[1], c2 = wcnt[2], c3 = wcnt[3];
    int base = nlist + (wv > 0 ? c0 : 0) + (wv > 1 ? c1 : 0) + (wv > 2 ? c2 : 0);
    if (isn) { js[base + wo] = (short)j; vf[base + wo] = (float)v; }
    nlist += c0 + c1 + c2 + c3;
    m_lb = fmax(m_lb, fmax(fmax(wfv[0], wfv[1]), fmax(wfv[2], wfv[3])));
    double rbnd = fmax(fmax(wbnd[0], wbnd[1]), fmax(wbnd[2], wbnd[3]));
    __syncthreads();
    if (-rbnd < m_lb - margin) break;
  }

  const float fm = (float)m_lb;
  float sw = 0.f;
  for (int c = t; c < nlist; c += 256) {
    float w = __expf(fabsf(vf[c]) - fm);
    vf[c] = w;
    sw += w;
  }
  for (int o = 32; o; o >>= 1) sw += __shfl_xor(sw, o, 64);
  if (lane == 0) redf[wv] = sw;
  __syncthreads();
  const float sumw = (redf[0] + redf[1]) + (redf[2] + redf[3]);

  const int ch = t & 63, g = t >> 6;
  float a0 = 0.f, a1 = 0.f;
  int c = g;
  for (; c + 4 < nlist; c += 8) {
    float w0 = vf[c], w1 = vf[c + 4];
    const float* K0 = K + (size_t)js[c] * OC;
    const float* K1 = K + (size_t)js[c + 4] * OC;
    float k00 = K0[ch], k01 = K0[64 + ch];
    float k10 = K1[ch], k11 = K1[64 + ch];
    a0 = fmaf(w0, k00, a0); a1 = fmaf(w0, k01, a1);
    a0 = fmaf(w1, k10, a0); a1 = fmaf(w1, k11, a1);
  }
  for (; c < nlist; c += 4) {
    float w = vf[c];
    const float* Kr = K + (size_t)js[c] * OC;
    a0 = fmaf(w, Kr[ch], a0);
    a1 = fmaf(w, Kr[64 + ch], a1);
  }
  hpart[g][ch] = a0;
  hpart[g][64 + ch] = a1;
  __syncthreads();
  if (t < 128) {
    float hv = (hpart[0][t] + hpart[1][t]) + (hpart[2][t] + hpart[3][t]);
    H[(size_t)i * OC + t] = hv / sumw;
  }
}

extern "C" void kernel_launch(void* const* d_in, const int* in_sizes, int n_in,
                              void* d_out, int out_size, void* d_ws, size_t ws_size,
                              hipStream_t stream) {
  const float* X    = (const float*)d_in[0];
  const int*   A    = (const int*)d_in[1];
  const float* U    = (const float*)d_in[2];
  const float* W    = (const float*)d_in[3];
  const float* a1   = (const float*)d_in[4];
  const float* a2   = (const float*)d_in[5];
  const float* lmbd = (const float*)d_in[6];
  float* H = (float*)d_out;

  const size_t wt_bytes  = (size_t)IC * OC * 4;
  const size_t bm_bytes  = (size_t)NN * NW * 4;
  const size_t dbl_bytes = (size_t)(7 * NN + 2 * IC + 2) * 8;

  // config cascade: (nsplit, G, MAXC); G=0 => fused fallback
  const int cfgs[11][3] = {{16,16,2048},{8,16,2048},{16,8,2048},{8,8,2048},{8,4,1536},
                           {4,4,1024},{2,4,1024},{8,0,0},{4,0,0},{2,0,0},{1,0,0}};
  int nsplit = 1, G = 0, MAXC = 0;
  for (int ci = 0; ci < 11; ci++) {
    int ns = cfgs[ci][0], g = cfgs[ci][1], mc = cfgs[ci][2];
    size_t need = (size_t)(ns > 1 ? ns + 1 : 1) * NNOC * 4 + wt_bytes + dbl_bytes +
                  (size_t)NN * 4 + bm_bytes + 1024;
    if (g > 0)
      need += (size_t)NN * mc * 2 + (size_t)NN * mc * 4 +
              (size_t)NN * g * OC * 4 + (size_t)NN * 8;
    if (need <= ws_size) { nsplit = ns; G = g; MAXC = mc; break; }
  }

  char* base = (char*)d_ws;
  float* Kp = (float*)base;
  float* Kf = (nsplit > 1) ? (float*)(base + (size_t)nsplit * NNOC * 4) : Kp;
  size_t off = (size_t)(nsplit > 1 ? nsplit + 1 : 1) * NNOC * 4;
  float* Wt = (float*)(base + off);            off += wt_bytes;
  double* dbl = (double*)(base + off);         off += dbl_bytes;
  double* k1  = dbl;
  double* k2  = k1 + NN;
  double* u1  = k2 + NN;
  double* sC  = u1 + NN;
  double* p   = sC + NN;
  double* q   = p  + NN;
  double* kvd = q  + NN;
  double* w1  = kvd + NN;
  double* w2  = w1 + IC;
  double* hdr = w2 + IC;
  int* sortedj = (int*)(base + off);           off += (size_t)NN * 4;
  unsigned* bm = (unsigned*)(base + off);      off += bm_bytes;
  float* wG = nullptr; float* Hpart = nullptr; float* sumwG = nullptr;
  int* nlistG = nullptr; short* jsG = nullptr;
  if (G > 0) {
    wG     = (float*)(base + off);             off += (size_t)NN * MAXC * 4;
    Hpart  = (float*)(base + off);             off += (size_t)NN * G * OC * 4;
    sumwG  = (float*)(base + off);             off += (size_t)NN * 4;
    nlistG = (int*)(base + off);               off += (size_t)NN * 4;
    jsG    = (short*)(base + off);             off += (size_t)NN * MAXC * 2;
  }

  const int chunk = (IC + nsplit - 1) / nsplit;

  bitmapA_zero<<<(NN * NW + 255) / 256, 256, 0, stream>>>(A, bm, u1, 2 * NN);
  transposeW<<<dim3((IC + 31) / 32, OC / 32), 256, 0, stream>>>(W, Wt);
  wvec_t<<<(IC + 3) / 4, 256, 0, stream>>>(Wt, a1, a2, w1, w2);
  xw<<<NN / 4, 256, 0, stream>>>(X, w1, w2, k1, k2);
  gemmK<<<dim3((NN + 31) / 32, nsplit), 256, 0, stream>>>(X, Wt, Kp, chunk);
  if (nsplit > 1)
    mergeK<<<(int)((NNOC / 4 + 255) / 256), 256, 0, stream>>>((const float4*)Kp, (float4*)Kf, nsplit);
  ut_reduce<<<dim3((NV + 255) / 256, (NN + 31) / 32), 256, 0, stream>>>((const float4*)U, k1, u1, sC);
  uv_kernel<<<NN / 4, 256, 0, stream>>>((const float4*)U, (const float4*)lmbd,
                                        (const double2*)u1, (const double2*)sC, p, q);
  sortk2<<<1, 1024, 0, stream>>>(k2, kvd, sortedj, hdr);
  if (G > 0) {
    softmax_walk<<<NN, 256, 0, stream>>>(bm, p, q, kvd, sortedj, hdr, jsG, wG, nlistG, sumwG, MAXC);
    gatherH<<<dim3(NN, G), 256, 0, stream>>>(jsG, wG, nlistG, Kf, Hpart, MAXC);
    reduceH<<<(int)((NNOC + 255) / 256), 256, 0, stream>>>(Hpart, sumwG, H, G);
  } else {
    softmaxH_fused<<<NN, 256, 0, stream>>>(bm, p, q, kvd, sortedj, hdr, Kf, H);
  }
}